// Round 9
// baseline (365.098 us; speedup 1.0000x reference)
//
#include <hip/hip_runtime.h>

#define BATCH  32
#define DIM    3072
#define NTRAIN 100000

/* k1 v4: counted-vmcnt pipeline */
#define KCH    128           /* k per chunk */
#define NCH    24            /* DIM / KCH */
#define ROWB   528           /* 512 B data + 16 B pad */
#define BUFB   (32 * ROWB)   /* 16896 B per buffer; 3 buffers = 50688 B */

/* selection */
#define NSEG   8
#define SEGJ   12500         /* NTRAIN / NSEG */
#define SEGCAP 1024
#define THRESH 25.0f

typedef __bf16 bf16x8 __attribute__((ext_vector_type(8)));
typedef float  f32x16 __attribute__((ext_vector_type(16)));
typedef unsigned short u16;
typedef unsigned int   u32;

union F8 { u16 us[8]; u32 ui[4]; uint4 u4; bf16x8 bf; };

__device__ __forceinline__ u16   bft(float f){ return (u16)(__float_as_uint(f) >> 16); }
__device__ __forceinline__ float bfh(float f){ return __uint_as_float(__float_as_uint(f) & 0xFFFF0000u); }

// ---------------- K0: split x into bf16 hi/lo ----------------
__global__ __launch_bounds__(256) void k0_split_x(
        const float* __restrict__ x, u16* __restrict__ xh, u16* __restrict__ xl) {
    int i = blockIdx.x * 256 + threadIdx.x;
    if (i >= BATCH * DIM) return;
    float f = x[i];
    xh[i] = bft(f);
    xl[i] = bft(f - bfh(f));
}

// ---------------- K1 v4: logits; triple-buffer + counted vmcnt + raw barrier ----------------
// 32 j-rows/block, 4 waves split k in quarters. Loop: wait vmcnt(8) [chunk c
// landed, chunk c+1 still in flight] + s_barrier; issue stage(c+2); compute c.
// No vmcnt(0) drain in the main loop -> HBM latency fully hidden.
__global__ __launch_bounds__(256) void k1_logits_v4(
        const float* __restrict__ train,
        const u16* __restrict__ xh, const u16* __restrict__ xl,
        const float* __restrict__ alphas, const int* __restrict__ tptr,
        float* __restrict__ logits) {
    __shared__ __align__(16) char smem[3 * BUFB];
    const int tid  = threadIdx.x;
    const int lane = tid & 63;
    const int w    = tid >> 6;
    const int l31  = lane & 31;
    const int g    = lane >> 5;
    const int jt0  = blockIdx.x * 32;

    const float ab = alphas[tptr[0]];
    const float s  = sqrtf(ab);
    const float om = 1.0f - ab;
    const float c1 = s / om;
    const float c2 = ab / (2.0f * om);

    const u16* xhr = xh + (size_t)l31 * DIM;
    const u16* xlr = xl + (size_t)l31 * DIM;
    const char* gblk = (const char*)train + (size_t)jt0 * (DIM * 4);

    f32x16 acc;
#pragma unroll
    for (int r = 0; r < 16; ++r) acc[r] = 0.0f;
    float tsqp = 0.0f;

    // wave w stages rows w*8 .. w*8+7 of chunk c (512 B each, lanes 0-31).
    // Exactly 8 VMEM ops per wave per call -> vmcnt arithmetic below.
    auto stage = [&](int buf, int c) {
        if (lane < 32) {
#pragma unroll
            for (int i = 0; i < 8; ++i) {
                const int r = w * 8 + i;
                const char* src = gblk + (size_t)r * (DIM * 4) + c * (KCH * 4) + lane * 16;
                char* dst = smem + buf * BUFB + r * ROWB;
                __builtin_amdgcn_global_load_lds(
                    (const __attribute__((address_space(1))) unsigned int*)src,
                    (__attribute__((address_space(3))) unsigned int*)dst,
                    16, 0, 0);
            }
        }
    };

    stage(0, 0);
    stage(1, 1);          // 16 loads in flight

    for (int c = 0; c < NCH; ++c) {
        // Wait for chunk c only (8 newest stay in flight), then join waves.
        // Single asm block: nothing (incl. LDS reads) can cross it.
        if (c < NCH - 1) {
            asm volatile("s_waitcnt vmcnt(8)\n\ts_barrier" ::: "memory");
        } else {
            asm volatile("s_waitcnt vmcnt(0)\n\ts_barrier" ::: "memory");
        }
        if (c + 2 < NCH) stage((c + 2) % 3, c + 2);   // overwrites buf read at c-1: done

        F8 ah[2], al[2];
#pragma unroll
        for (int s4 = 0; s4 < 2; ++s4) {
            const int kglob = c * KCH + w * 32 + s4 * 16 + g * 8;
            ah[s4].u4 = *(const uint4*)(xhr + kglob);
            al[s4].u4 = *(const uint4*)(xlr + kglob);
        }

        const char* lb = smem + (c % 3) * BUFB + l31 * ROWB;
#pragma unroll
        for (int s4 = 0; s4 < 2; ++s4) {
            const u32 kb0 = (u32)(w * 128 + s4 * 64 + g * 32);
            const float4 f0 = *(const float4*)(lb + kb0);
            const float4 f1 = *(const float4*)(lb + kb0 + 16);
            float fv[8] = {f0.x, f0.y, f0.z, f0.w, f1.x, f1.y, f1.z, f1.w};
            F8 bh, bl;
#pragma unroll
            for (int e = 0; e < 8; ++e) {
                float f = fv[e];
                bh.us[e] = bft(f);
                bl.us[e] = bft(f - bfh(f));
                tsqp = fmaf(f, f, tsqp);
            }
            acc = __builtin_amdgcn_mfma_f32_32x32x16_bf16(ah[s4].bf, bh.bf, acc, 0, 0, 0);
            acc = __builtin_amdgcn_mfma_f32_32x32x16_bf16(al[s4].bf, bh.bf, acc, 0, 0, 0);
            acc = __builtin_amdgcn_mfma_f32_32x32x16_bf16(ah[s4].bf, bl.bf, acc, 0, 0, 0);
        }
    }
    __syncthreads();      // all compute done; smem reusable for the reduce

    // ---- cross-wave reduce (acc over k-quarters) + tsq, then logits write ----
    tsqp += __shfl_xor(tsqp, 32);
    float* red = (float*)smem;
    if (w > 0) {
        float* dp = red + ((w - 1) * 64 + lane) * 16;
#pragma unroll
        for (int r = 0; r < 16; ++r) dp[r] = acc[r];
    }
    if (g == 0) red[3072 + w * 32 + l31] = tsqp;
    __syncthreads();
    if (w == 0) {
#pragma unroll
        for (int q = 0; q < 3; ++q) {
            const float* sp = red + (q * 64 + lane) * 16;
#pragma unroll
            for (int r = 0; r < 16; ++r) acc[r] += sp[r];
        }
        const float tsq = red[3072 + l31] + red[3072 + 32 + l31]
                        + red[3072 + 64 + l31] + red[3072 + 96 + l31];
#pragma unroll
        for (int r = 0; r < 16; ++r) {
            int brow = (r & 3) + 8 * (r >> 2) + 4 * g;
            logits[(size_t)brow * NTRAIN + jt0 + l31] = c1 * acc[r] - c2 * tsq;
        }
    }
}

// ---------------- K2a: per-segment row max (256 blocks) ----------------
__global__ __launch_bounds__(256) void k2a_rowmax(
        const float* __restrict__ logits, float* __restrict__ m_part) {
    const int b   = blockIdx.x >> 3;
    const int seg = blockIdx.x & 7;
    const int j0  = seg * SEGJ;
    const int j1  = min(j0 + SEGJ, NTRAIN);
    const float* row = logits + (size_t)b * NTRAIN;
    float mx = -3.0e38f;
    for (int j = j0 + threadIdx.x; j < j1; j += 256) mx = fmaxf(mx, row[j]);
    __shared__ float red[256];
    red[threadIdx.x] = mx;
    __syncthreads();
    for (int off = 128; off > 0; off >>= 1) {
        if (threadIdx.x < (unsigned)off)
            red[threadIdx.x] = fmaxf(red[threadIdx.x], red[threadIdx.x + off]);
        __syncthreads();
    }
    if (threadIdx.x == 0) m_part[blockIdx.x] = red[0];
}

// ---------------- K2b: deterministic top-weight selection ----------------
__global__ __launch_bounds__(256) void k2b_select(
        const float* __restrict__ logits, const float* __restrict__ m_part,
        int* __restrict__ idx, float* __restrict__ wts,
        int* __restrict__ cnt, float* __restrict__ lsum) {
    const int b   = blockIdx.x >> 3;
    const int seg = blockIdx.x & 7;
    const int tid = threadIdx.x;
    float mb = -3.0e38f;
#pragma unroll
    for (int sg = 0; sg < NSEG; ++sg) mb = fmaxf(mb, m_part[b * NSEG + sg]);
    const int j0 = seg * SEGJ;
    const int j1 = min(j0 + SEGJ, NTRAIN);
    const float* lrow = logits + (size_t)b * NTRAIN;

    int mycnt = 0;
    for (int j = j0 + tid; j < j1; j += 256)
        if (lrow[j] >= mb - THRESH) ++mycnt;

    __shared__ int   soff[257];
    __shared__ float ssum[256];
    soff[tid + 1] = mycnt;
    __syncthreads();
    if (tid == 0) {
        soff[0] = 0;
        for (int t = 1; t <= 256; ++t) soff[t] += soff[t - 1];
    }
    __syncthreads();

    int off = soff[tid];
    const int base = (b * NSEG + seg) * SEGCAP;
    float mysum = 0.0f;
    for (int j = j0 + tid; j < j1; j += 256) {
        float lg = lrow[j];
        if (lg >= mb - THRESH) {
            float wv = __expf(lg - mb);
            mysum += wv;
            if (off < SEGCAP) { idx[base + off] = j; wts[base + off] = wv; }
            ++off;
        }
    }
    ssum[tid] = mysum;
    __syncthreads();
    if (tid == 0) {
        float Ls = 0.0f;
        for (int t = 0; t < 256; ++t) Ls += ssum[t];
        lsum[b * NSEG + seg] = Ls;
        cnt[b * NSEG + seg]  = min(soff[256], SEGCAP);
    }
}

// ---------------- K3: gather-PV over selected rows + final output (all f32) ----------------
__global__ __launch_bounds__(256) void k3_gather(
        const float* __restrict__ x, const float* __restrict__ train,
        const int* __restrict__ idx, const float* __restrict__ wts,
        const int* __restrict__ cnt, const float* __restrict__ lsum,
        const float* __restrict__ alphas, const int* __restrict__ tptr,
        float* __restrict__ out) {
    const int blk  = blockIdx.x;       // b*12 + dseg
    const int b    = blk / 12;
    const int dseg = blk % 12;
    const int d    = dseg * 256 + threadIdx.x;

    const float ab  = alphas[tptr[0]];
    const float s   = sqrtf(ab);
    const float om  = 1.0f - ab;
    const float inv = 1.0f / sqrtf(om);

    float L = 0.0f;
#pragma unroll
    for (int sg = 0; sg < NSEG; ++sg) L += lsum[b * NSEG + sg];

    float acc = 0.0f;
    for (int sg = 0; sg < NSEG; ++sg) {
        const int n    = cnt[b * NSEG + sg];
        const int base = (b * NSEG + sg) * SEGCAP;
        for (int i = 0; i < n; ++i) {
            const int   j = idx[base + i];
            const float w = wts[base + i];
            acc = fmaf(w, train[(size_t)j * DIM + d], acc);
        }
    }
    const size_t o = (size_t)b * DIM + d;
    out[o] = inv * x[o] - s * inv * (acc / L);
}

extern "C" void kernel_launch(void* const* d_in, const int* in_sizes, int n_in,
                              void* d_out, int out_size, void* d_ws, size_t ws_size,
                              hipStream_t stream) {
    const float* x      = (const float*)d_in[0];
    const float* train  = (const float*)d_in[1];
    const float* alphas = (const float*)d_in[2];
    const int*   tptr   = (const int*)d_in[3];
    float* out = (float*)d_out;

    char* ws = (char*)d_ws;
    float* logits = (float*)ws;                         // 12,800,000 B
    float* m_part = (float*)(ws + 12800000);            //      1,024 B
    float* lsum   = (float*)(ws + 12801024);            //      1,024 B
    int*   cnt    = (int*)(ws + 12802048);              //      1,024 B
    int*   idx    = (int*)(ws + 12803072);              //  1,048,576 B
    float* wts    = (float*)(ws + 13851648);            //  1,048,576 B
    u16*   xh     = (u16*)(ws + 14900224);              //    196,608 B
    u16*   xl     = (u16*)(ws + 15096832);              //    196,608 B

    k0_split_x<<<(BATCH * DIM + 255) / 256, 256, 0, stream>>>(x, xh, xl);
    k1_logits_v4<<<NTRAIN / 32, 256, 0, stream>>>(train, xh, xl, alphas, tptr, logits);
    k2a_rowmax<<<BATCH * NSEG, 256, 0, stream>>>(logits, m_part);
    k2b_select<<<BATCH * NSEG, 256, 0, stream>>>(logits, m_part, idx, wts, cnt, lsum);
    k3_gather<<<BATCH * 12, 256, 0, stream>>>(x, train, idx, wts, cnt, lsum,
                                              alphas, tptr, out);
}

// Round 10
// 352.268 us; speedup vs baseline: 1.0364x; 1.0364x over previous
//
#include <hip/hip_runtime.h>

#define BATCH  32
#define DIM    3072
#define NTRAIN 100000

/* k1 v5: counted-vmcnt pipeline, x-frags pipelined one chunk ahead */
#define KCH    128           /* k per chunk */
#define NCH    24            /* DIM / KCH */
#define ROWB   528           /* 512 B data + 16 B pad */
#define BUFB   (32 * ROWB)   /* 16896 B per buffer; 3 buffers = 50688 B */

/* selection */
#define NSEG   8
#define SEGJ   12500         /* NTRAIN / NSEG */
#define SEGCAP 1024
#define THRESH 25.0f

typedef __bf16 bf16x8 __attribute__((ext_vector_type(8)));
typedef float  f32x16 __attribute__((ext_vector_type(16)));
typedef unsigned short u16;
typedef unsigned int   u32;

union F8 { u16 us[8]; u32 ui[4]; uint4 u4; bf16x8 bf; };

__device__ __forceinline__ u16   bft(float f){ return (u16)(__float_as_uint(f) >> 16); }
__device__ __forceinline__ float bfh(float f){ return __uint_as_float(__float_as_uint(f) & 0xFFFF0000u); }

// ---------------- K0: split x into bf16 hi/lo ----------------
__global__ __launch_bounds__(256) void k0_split_x(
        const float* __restrict__ x, u16* __restrict__ xh, u16* __restrict__ xl) {
    int i = blockIdx.x * 256 + threadIdx.x;
    if (i >= BATCH * DIM) return;
    float f = x[i];
    xh[i] = bft(f);
    xl[i] = bft(f - bfh(f));
}

// ---------------- K1 v5: logits; triple-buffer, counted vmcnt, pipelined x-frags ----------------
// Issue order per iter c: [wait vmcnt(8); barrier] -> xfrag(c+1) -> stage(c+2)
// -> compute(c). Steady-state outstanding at wait: stage(c) 8, xfrag(c) 4,
// stage(c+1) 8 => vmcnt(8) retires exactly {stage(c), xfrag(c)}; stage(c+1)
// flies across the barrier. No vmcnt(0) drain in the loop.
__global__ __launch_bounds__(256) void k1_logits_v5(
        const float* __restrict__ train,
        const u16* __restrict__ xh, const u16* __restrict__ xl,
        const float* __restrict__ alphas, const int* __restrict__ tptr,
        float* __restrict__ logits) {
    __shared__ __align__(16) char smem[3 * BUFB];
    const int tid  = threadIdx.x;
    const int lane = tid & 63;
    const int w    = tid >> 6;
    const int l31  = lane & 31;
    const int g    = lane >> 5;
    const int jt0  = blockIdx.x * 32;

    const float ab = alphas[tptr[0]];
    const float s  = sqrtf(ab);
    const float om = 1.0f - ab;
    const float c1 = s / om;
    const float c2 = ab / (2.0f * om);

    const u16* xhr = xh + (size_t)l31 * DIM;
    const u16* xlr = xl + (size_t)l31 * DIM;
    const char* gblk = (const char*)train + (size_t)jt0 * (DIM * 4);

    f32x16 acc;
#pragma unroll
    for (int r = 0; r < 16; ++r) acc[r] = 0.0f;
    float tsqp = 0.0f;

    // wave w stages rows w*8 .. w*8+7 of chunk c (512 B each, lanes 0-31).
    // Exactly 8 VMEM ops per wave per call.
    auto stage = [&](int buf, int c) {
        if (lane < 32) {
#pragma unroll
            for (int i = 0; i < 8; ++i) {
                const int r = w * 8 + i;
                const char* src = gblk + (size_t)r * (DIM * 4) + c * (KCH * 4) + lane * 16;
                char* dst = smem + buf * BUFB + r * ROWB;
                __builtin_amdgcn_global_load_lds(
                    (const __attribute__((address_space(1))) unsigned int*)src,
                    (__attribute__((address_space(3))) unsigned int*)dst,
                    16, 0, 0);
            }
        }
    };
    // x-fragment loads for chunk c: exactly 4 VMEM ops per wave
    auto ldx = [&](int c, F8* ah, F8* al) {
#pragma unroll
        for (int s4 = 0; s4 < 2; ++s4) {
            const int kglob = c * KCH + w * 32 + s4 * 16 + g * 8;
            ah[s4].u4 = *(const uint4*)(xhr + kglob);
            al[s4].u4 = *(const uint4*)(xlr + kglob);
        }
    };

    F8 ahc[2], alc[2];
    // prologue order fixed: stage(0) [8], xfrag(0) [4], stage(1) [8]
    stage(0, 0);
    __builtin_amdgcn_sched_barrier(0);
    ldx(0, ahc, alc);
    __builtin_amdgcn_sched_barrier(0);
    stage(1, 1);

    for (int c = 0; c < NCH; ++c) {
        if (c < NCH - 1) {
            asm volatile("s_waitcnt vmcnt(8)\n\ts_barrier" ::: "memory");
        } else {
            asm volatile("s_waitcnt vmcnt(0)\n\ts_barrier" ::: "memory");
        }

        F8 ahn[2], aln[2];
        if (c + 1 < NCH) ldx(c + 1, ahn, aln);      // issued BEFORE next stage
        __builtin_amdgcn_sched_barrier(0);
        if (c + 2 < NCH) stage((c + 2) % 3, c + 2); // overwrites buf read at c-1: done
        __builtin_amdgcn_sched_barrier(0);

        const char* lb = smem + (c % 3) * BUFB + l31 * ROWB;
#pragma unroll
        for (int s4 = 0; s4 < 2; ++s4) {
            const u32 kb0 = (u32)(w * 128 + s4 * 64 + g * 32);
            const float4 f0 = *(const float4*)(lb + kb0);
            const float4 f1 = *(const float4*)(lb + kb0 + 16);
            float fv[8] = {f0.x, f0.y, f0.z, f0.w, f1.x, f1.y, f1.z, f1.w};
            F8 bh, bl;
#pragma unroll
            for (int e = 0; e < 8; ++e) {
                float f = fv[e];
                bh.us[e] = bft(f);
                bl.us[e] = bft(f - bfh(f));
                tsqp = fmaf(f, f, tsqp);
            }
            acc = __builtin_amdgcn_mfma_f32_32x32x16_bf16(ahc[s4].bf, bh.bf, acc, 0, 0, 0);
            acc = __builtin_amdgcn_mfma_f32_32x32x16_bf16(alc[s4].bf, bh.bf, acc, 0, 0, 0);
            acc = __builtin_amdgcn_mfma_f32_32x32x16_bf16(ahc[s4].bf, bl.bf, acc, 0, 0, 0);
        }
        if (c + 1 < NCH) {
            ahc[0] = ahn[0]; ahc[1] = ahn[1];
            alc[0] = aln[0]; alc[1] = aln[1];
        }
    }
    __syncthreads();      // all compute done; smem reusable for the reduce

    // ---- cross-wave reduce (acc over k-quarters) + tsq, then logits write ----
    tsqp += __shfl_xor(tsqp, 32);
    float* red = (float*)smem;
    if (w > 0) {
        float* dp = red + ((w - 1) * 64 + lane) * 16;
#pragma unroll
        for (int r = 0; r < 16; ++r) dp[r] = acc[r];
    }
    if (g == 0) red[3072 + w * 32 + l31] = tsqp;
    __syncthreads();
    if (w == 0) {
#pragma unroll
        for (int q = 0; q < 3; ++q) {
            const float* sp = red + (q * 64 + lane) * 16;
#pragma unroll
            for (int r = 0; r < 16; ++r) acc[r] += sp[r];
        }
        const float tsq = red[3072 + l31] + red[3072 + 32 + l31]
                        + red[3072 + 64 + l31] + red[3072 + 96 + l31];
#pragma unroll
        for (int r = 0; r < 16; ++r) {
            int brow = (r & 3) + 8 * (r >> 2) + 4 * g;
            logits[(size_t)brow * NTRAIN + jt0 + l31] = c1 * acc[r] - c2 * tsq;
        }
    }
}

// ---------------- K2a: per-segment row max (256 blocks) ----------------
__global__ __launch_bounds__(256) void k2a_rowmax(
        const float* __restrict__ logits, float* __restrict__ m_part) {
    const int b   = blockIdx.x >> 3;
    const int seg = blockIdx.x & 7;
    const int j0  = seg * SEGJ;
    const int j1  = min(j0 + SEGJ, NTRAIN);
    const float* row = logits + (size_t)b * NTRAIN;
    float mx = -3.0e38f;
    for (int j = j0 + threadIdx.x; j < j1; j += 256) mx = fmaxf(mx, row[j]);
    __shared__ float red[256];
    red[threadIdx.x] = mx;
    __syncthreads();
    for (int off = 128; off > 0; off >>= 1) {
        if (threadIdx.x < (unsigned)off)
            red[threadIdx.x] = fmaxf(red[threadIdx.x], red[threadIdx.x + off]);
        __syncthreads();
    }
    if (threadIdx.x == 0) m_part[blockIdx.x] = red[0];
}

// ---------------- K2b: deterministic top-weight selection ----------------
__global__ __launch_bounds__(256) void k2b_select(
        const float* __restrict__ logits, const float* __restrict__ m_part,
        int* __restrict__ idx, float* __restrict__ wts,
        int* __restrict__ cnt, float* __restrict__ lsum) {
    const int b   = blockIdx.x >> 3;
    const int seg = blockIdx.x & 7;
    const int tid = threadIdx.x;
    float mb = -3.0e38f;
#pragma unroll
    for (int sg = 0; sg < NSEG; ++sg) mb = fmaxf(mb, m_part[b * NSEG + sg]);
    const int j0 = seg * SEGJ;
    const int j1 = min(j0 + SEGJ, NTRAIN);
    const float* lrow = logits + (size_t)b * NTRAIN;

    int mycnt = 0;
    for (int j = j0 + tid; j < j1; j += 256)
        if (lrow[j] >= mb - THRESH) ++mycnt;

    __shared__ int   soff[257];
    __shared__ float ssum[256];
    soff[tid + 1] = mycnt;
    __syncthreads();
    if (tid == 0) {
        soff[0] = 0;
        for (int t = 1; t <= 256; ++t) soff[t] += soff[t - 1];
    }
    __syncthreads();

    int off = soff[tid];
    const int base = (b * NSEG + seg) * SEGCAP;
    float mysum = 0.0f;
    for (int j = j0 + tid; j < j1; j += 256) {
        float lg = lrow[j];
        if (lg >= mb - THRESH) {
            float wv = __expf(lg - mb);
            mysum += wv;
            if (off < SEGCAP) { idx[base + off] = j; wts[base + off] = wv; }
            ++off;
        }
    }
    ssum[tid] = mysum;
    __syncthreads();
    if (tid == 0) {
        float Ls = 0.0f;
        for (int t = 0; t < 256; ++t) Ls += ssum[t];
        lsum[b * NSEG + seg] = Ls;
        cnt[b * NSEG + seg]  = min(soff[256], SEGCAP);
    }
}

// ---------------- K3: gather-PV over selected rows + final output (all f32) ----------------
__global__ __launch_bounds__(256) void k3_gather(
        const float* __restrict__ x, const float* __restrict__ train,
        const int* __restrict__ idx, const float* __restrict__ wts,
        const int* __restrict__ cnt, const float* __restrict__ lsum,
        const float* __restrict__ alphas, const int* __restrict__ tptr,
        float* __restrict__ out) {
    const int blk  = blockIdx.x;       // b*12 + dseg
    const int b    = blk / 12;
    const int dseg = blk % 12;
    const int d    = dseg * 256 + threadIdx.x;

    const float ab  = alphas[tptr[0]];
    const float s   = sqrtf(ab);
    const float om  = 1.0f - ab;
    const float inv = 1.0f / sqrtf(om);

    float L = 0.0f;
#pragma unroll
    for (int sg = 0; sg < NSEG; ++sg) L += lsum[b * NSEG + sg];

    float acc = 0.0f;
    for (int sg = 0; sg < NSEG; ++sg) {
        const int n    = cnt[b * NSEG + sg];
        const int base = (b * NSEG + sg) * SEGCAP;
        for (int i = 0; i < n; ++i) {
            const int   j = idx[base + i];
            const float w = wts[base + i];
            acc = fmaf(w, train[(size_t)j * DIM + d], acc);
        }
    }
    const size_t o = (size_t)b * DIM + d;
    out[o] = inv * x[o] - s * inv * (acc / L);
}

extern "C" void kernel_launch(void* const* d_in, const int* in_sizes, int n_in,
                              void* d_out, int out_size, void* d_ws, size_t ws_size,
                              hipStream_t stream) {
    const float* x      = (const float*)d_in[0];
    const float* train  = (const float*)d_in[1];
    const float* alphas = (const float*)d_in[2];
    const int*   tptr   = (const int*)d_in[3];
    float* out = (float*)d_out;

    char* ws = (char*)d_ws;
    float* logits = (float*)ws;                         // 12,800,000 B
    float* m_part = (float*)(ws + 12800000);            //      1,024 B
    float* lsum   = (float*)(ws + 12801024);            //      1,024 B
    int*   cnt    = (int*)(ws + 12802048);              //      1,024 B
    int*   idx    = (int*)(ws + 12803072);              //  1,048,576 B
    float* wts    = (float*)(ws + 13851648);            //  1,048,576 B
    u16*   xh     = (u16*)(ws + 14900224);              //    196,608 B
    u16*   xl     = (u16*)(ws + 15096832);              //    196,608 B

    k0_split_x<<<(BATCH * DIM + 255) / 256, 256, 0, stream>>>(x, xh, xl);
    k1_logits_v5<<<NTRAIN / 32, 256, 0, stream>>>(train, xh, xl, alphas, tptr, logits);
    k2a_rowmax<<<BATCH * NSEG, 256, 0, stream>>>(logits, m_part);
    k2b_select<<<BATCH * NSEG, 256, 0, stream>>>(logits, m_part, idx, wts, cnt, lsum);
    k3_gather<<<BATCH * 12, 256, 0, stream>>>(x, train, idx, wts, cnt, lsum,
                                              alphas, tptr, out);
}

// Round 11
// 315.783 us; speedup vs baseline: 1.1562x; 1.1155x over previous
//
#include <hip/hip_runtime.h>

#define BATCH  32
#define DIM    3072
#define NTRAIN 100000

/* k1 v6: counted-vmcnt pipeline + fragment-ordered x loads */
#define KCH    128           /* k per chunk */
#define NCH    24            /* DIM / KCH */
#define ROWB   528           /* 512 B data + 16 B pad (4-way read conflicts: floor) */
#define BUFB   (32 * ROWB)   /* 16896 B per buffer; 3 buffers = 50688 B */

/* selection */
#define NSEG   8
#define SEGJ   12500         /* NTRAIN / NSEG */
#define SEGCAP 1024
#define THRESH 25.0f

typedef __bf16 bf16x8 __attribute__((ext_vector_type(8)));
typedef float  f32x16 __attribute__((ext_vector_type(16)));
typedef unsigned short u16;
typedef unsigned int   u32;

union F8 { u16 us[8]; u32 ui[4]; uint4 u4; bf16x8 bf; };

__device__ __forceinline__ u16   bft(float f){ return (u16)(__float_as_uint(f) >> 16); }
__device__ __forceinline__ float bfh(float f){ return __uint_as_float(__float_as_uint(f) & 0xFFFF0000u); }

// ---------------- K0 v2: split x into bf16 hi/lo, FRAGMENT-ORDERED ----------------
// Layout: [kb16 0..191][row 0..31][g 0..1][8 u16]  (off = kb*512 + r*16 + g*8).
// k1's wave fragment load = one dense 1 KB span (fully coalesced L2 hits).
__global__ __launch_bounds__(256) void k0_split_x_v2(
        const float* __restrict__ x, u16* __restrict__ xfh, u16* __restrict__ xfl) {
    int task = blockIdx.x * 256 + threadIdx.x;   // 12288 tasks
    if (task >= 12288) return;
    int kb  = task >> 6;          // 0..191
    int rem = task & 63;
    int r   = rem >> 1;           // 0..31
    int g   = rem & 1;
    const float* src = x + r * DIM + kb * 16 + g * 8;
    float4 A = *(const float4*)(src);
    float4 B = *(const float4*)(src + 4);
    float fv[8] = {A.x, A.y, A.z, A.w, B.x, B.y, B.z, B.w};
    F8 h, l;
#pragma unroll
    for (int e = 0; e < 8; ++e) {
        h.us[e] = bft(fv[e]);
        l.us[e] = bft(fv[e] - bfh(fv[e]));
    }
    size_t off = (size_t)kb * 512 + r * 16 + g * 8;
    *(uint4*)(xfh + off) = h.u4;
    *(uint4*)(xfl + off) = l.u4;
}

// ---------------- K1 v6: logits; triple-buffer, counted vmcnt, coalesced x-frags ----------------
// Issue order per iter c: [wait vmcnt(8); barrier] -> xfrag(c+1) -> stage(c+2)
// -> compute(c). Steady-state outstanding at the wait: stage(c) 8 + xfrag(c) 4
// + stage(c+1) 8 => vmcnt(8) retires exactly {stage(c), xfrag(c)}.
__global__ __launch_bounds__(256) void k1_logits_v6(
        const float* __restrict__ train,
        const u16* __restrict__ xfh, const u16* __restrict__ xfl,
        const float* __restrict__ alphas, const int* __restrict__ tptr,
        float* __restrict__ logits) {
    __shared__ __align__(16) char smem[3 * BUFB];
    const int tid  = threadIdx.x;
    const int lane = tid & 63;
    const int w    = tid >> 6;
    const int l31  = lane & 31;
    const int g    = lane >> 5;
    const int jt0  = blockIdx.x * 32;

    const float ab = alphas[tptr[0]];
    const float s  = sqrtf(ab);
    const float om = 1.0f - ab;
    const float c1 = s / om;
    const float c2 = ab / (2.0f * om);

    const char* gblk = (const char*)train + (size_t)jt0 * (DIM * 4);

    f32x16 acc;
#pragma unroll
    for (int r = 0; r < 16; ++r) acc[r] = 0.0f;
    float tsqp = 0.0f;

    // wave w stages rows w*8 .. w*8+7 of chunk c (512 B each, lanes 0-31).
    // Exactly 8 VMEM ops per wave per call.
    auto stage = [&](int buf, int c) {
        if (lane < 32) {
#pragma unroll
            for (int i = 0; i < 8; ++i) {
                const int r = w * 8 + i;
                const char* src = gblk + (size_t)r * (DIM * 4) + c * (KCH * 4) + lane * 16;
                char* dst = smem + buf * BUFB + r * ROWB;
                __builtin_amdgcn_global_load_lds(
                    (const __attribute__((address_space(1))) unsigned int*)src,
                    (__attribute__((address_space(3))) unsigned int*)dst,
                    16, 0, 0);
            }
        }
    };
    // x-fragment loads for chunk c: 4 VMEM ops per wave, each a dense 1 KB span
    auto ldx = [&](int c, F8* ah, F8* al) {
#pragma unroll
        for (int s4 = 0; s4 < 2; ++s4) {
            const int kb16 = c * 8 + w * 2 + s4;
            const size_t off = (size_t)kb16 * 512 + l31 * 16 + g * 8;
            ah[s4].u4 = *(const uint4*)(xfh + off);
            al[s4].u4 = *(const uint4*)(xfl + off);
        }
    };

    F8 ahc[2], alc[2];
    // prologue order fixed: stage(0) [8], xfrag(0) [4], stage(1) [8]
    stage(0, 0);
    __builtin_amdgcn_sched_barrier(0);
    ldx(0, ahc, alc);
    __builtin_amdgcn_sched_barrier(0);
    stage(1, 1);

    for (int c = 0; c < NCH; ++c) {
        if (c < NCH - 1) {
            asm volatile("s_waitcnt vmcnt(8)\n\ts_barrier" ::: "memory");
        } else {
            asm volatile("s_waitcnt vmcnt(0)\n\ts_barrier" ::: "memory");
        }

        F8 ahn[2], aln[2];
        if (c + 1 < NCH) ldx(c + 1, ahn, aln);      // issued BEFORE next stage
        __builtin_amdgcn_sched_barrier(0);
        if (c + 2 < NCH) stage((c + 2) % 3, c + 2); // overwrites buf read at c-1: done
        __builtin_amdgcn_sched_barrier(0);

        const char* lb = smem + (c % 3) * BUFB + l31 * ROWB;
#pragma unroll
        for (int s4 = 0; s4 < 2; ++s4) {
            const u32 kb0 = (u32)(w * 128 + s4 * 64 + g * 32);
            const float4 f0 = *(const float4*)(lb + kb0);
            const float4 f1 = *(const float4*)(lb + kb0 + 16);
            float fv[8] = {f0.x, f0.y, f0.z, f0.w, f1.x, f1.y, f1.z, f1.w};
            F8 bh, bl;
#pragma unroll
            for (int e = 0; e < 8; ++e) {
                float f = fv[e];
                bh.us[e] = bft(f);
                bl.us[e] = bft(f - bfh(f));
                tsqp = fmaf(f, f, tsqp);
            }
            acc = __builtin_amdgcn_mfma_f32_32x32x16_bf16(ahc[s4].bf, bh.bf, acc, 0, 0, 0);
            acc = __builtin_amdgcn_mfma_f32_32x32x16_bf16(alc[s4].bf, bh.bf, acc, 0, 0, 0);
            acc = __builtin_amdgcn_mfma_f32_32x32x16_bf16(ahc[s4].bf, bl.bf, acc, 0, 0, 0);
        }
        if (c + 1 < NCH) {
            ahc[0] = ahn[0]; ahc[1] = ahn[1];
            alc[0] = aln[0]; alc[1] = aln[1];
        }
    }
    __syncthreads();      // all compute done; smem reusable for the reduce

    // ---- cross-wave reduce (acc over k-quarters) + tsq, then logits write ----
    tsqp += __shfl_xor(tsqp, 32);
    float* red = (float*)smem;
    if (w > 0) {
        float* dp = red + ((w - 1) * 64 + lane) * 16;
#pragma unroll
        for (int r = 0; r < 16; ++r) dp[r] = acc[r];
    }
    if (g == 0) red[3072 + w * 32 + l31] = tsqp;
    __syncthreads();
    if (w == 0) {
#pragma unroll
        for (int q = 0; q < 3; ++q) {
            const float* sp = red + (q * 64 + lane) * 16;
#pragma unroll
            for (int r = 0; r < 16; ++r) acc[r] += sp[r];
        }
        const float tsq = red[3072 + l31] + red[3072 + 32 + l31]
                        + red[3072 + 64 + l31] + red[3072 + 96 + l31];
#pragma unroll
        for (int r = 0; r < 16; ++r) {
            int brow = (r & 3) + 8 * (r >> 2) + 4 * g;
            logits[(size_t)brow * NTRAIN + jt0 + l31] = c1 * acc[r] - c2 * tsq;
        }
    }
}

// ---------------- K2a: per-segment row max (256 blocks) ----------------
__global__ __launch_bounds__(256) void k2a_rowmax(
        const float* __restrict__ logits, float* __restrict__ m_part) {
    const int b   = blockIdx.x >> 3;
    const int seg = blockIdx.x & 7;
    const int j0  = seg * SEGJ;
    const int j1  = min(j0 + SEGJ, NTRAIN);
    const float* row = logits + (size_t)b * NTRAIN;
    float mx = -3.0e38f;
    for (int j = j0 + threadIdx.x; j < j1; j += 256) mx = fmaxf(mx, row[j]);
    __shared__ float red[256];
    red[threadIdx.x] = mx;
    __syncthreads();
    for (int off = 128; off > 0; off >>= 1) {
        if (threadIdx.x < (unsigned)off)
            red[threadIdx.x] = fmaxf(red[threadIdx.x], red[threadIdx.x + off]);
        __syncthreads();
    }
    if (threadIdx.x == 0) m_part[blockIdx.x] = red[0];
}

// ---------------- K2b: deterministic top-weight selection ----------------
__global__ __launch_bounds__(256) void k2b_select(
        const float* __restrict__ logits, const float* __restrict__ m_part,
        int* __restrict__ idx, float* __restrict__ wts,
        int* __restrict__ cnt, float* __restrict__ lsum) {
    const int b   = blockIdx.x >> 3;
    const int seg = blockIdx.x & 7;
    const int tid = threadIdx.x;
    float mb = -3.0e38f;
#pragma unroll
    for (int sg = 0; sg < NSEG; ++sg) mb = fmaxf(mb, m_part[b * NSEG + sg]);
    const int j0 = seg * SEGJ;
    const int j1 = min(j0 + SEGJ, NTRAIN);
    const float* lrow = logits + (size_t)b * NTRAIN;

    int mycnt = 0;
    for (int j = j0 + tid; j < j1; j += 256)
        if (lrow[j] >= mb - THRESH) ++mycnt;

    __shared__ int   soff[257];
    __shared__ float ssum[256];
    soff[tid + 1] = mycnt;
    __syncthreads();
    if (tid == 0) {
        soff[0] = 0;
        for (int t = 1; t <= 256; ++t) soff[t] += soff[t - 1];
    }
    __syncthreads();

    int off = soff[tid];
    const int base = (b * NSEG + seg) * SEGCAP;
    float mysum = 0.0f;
    for (int j = j0 + tid; j < j1; j += 256) {
        float lg = lrow[j];
        if (lg >= mb - THRESH) {
            float wv = __expf(lg - mb);
            mysum += wv;
            if (off < SEGCAP) { idx[base + off] = j; wts[base + off] = wv; }
            ++off;
        }
    }
    ssum[tid] = mysum;
    __syncthreads();
    if (tid == 0) {
        float Ls = 0.0f;
        for (int t = 0; t < 256; ++t) Ls += ssum[t];
        lsum[b * NSEG + seg] = Ls;
        cnt[b * NSEG + seg]  = min(soff[256], SEGCAP);
    }
}

// ---------------- K3: gather-PV over selected rows + final output (all f32) ----------------
__global__ __launch_bounds__(256) void k3_gather(
        const float* __restrict__ x, const float* __restrict__ train,
        const int* __restrict__ idx, const float* __restrict__ wts,
        const int* __restrict__ cnt, const float* __restrict__ lsum,
        const float* __restrict__ alphas, const int* __restrict__ tptr,
        float* __restrict__ out) {
    const int blk  = blockIdx.x;       // b*12 + dseg
    const int b    = blk / 12;
    const int dseg = blk % 12;
    const int d    = dseg * 256 + threadIdx.x;

    const float ab  = alphas[tptr[0]];
    const float s   = sqrtf(ab);
    const float om  = 1.0f - ab;
    const float inv = 1.0f / sqrtf(om);

    float L = 0.0f;
#pragma unroll
    for (int sg = 0; sg < NSEG; ++sg) L += lsum[b * NSEG + sg];

    float acc = 0.0f;
    for (int sg = 0; sg < NSEG; ++sg) {
        const int n    = cnt[b * NSEG + sg];
        const int base = (b * NSEG + sg) * SEGCAP;
        for (int i = 0; i < n; ++i) {
            const int   j = idx[base + i];
            const float w = wts[base + i];
            acc = fmaf(w, train[(size_t)j * DIM + d], acc);
        }
    }
    const size_t o = (size_t)b * DIM + d;
    out[o] = inv * x[o] - s * inv * (acc / L);
}

extern "C" void kernel_launch(void* const* d_in, const int* in_sizes, int n_in,
                              void* d_out, int out_size, void* d_ws, size_t ws_size,
                              hipStream_t stream) {
    const float* x      = (const float*)d_in[0];
    const float* train  = (const float*)d_in[1];
    const float* alphas = (const float*)d_in[2];
    const int*   tptr   = (const int*)d_in[3];
    float* out = (float*)d_out;

    char* ws = (char*)d_ws;
    float* logits = (float*)ws;                         // 12,800,000 B
    float* m_part = (float*)(ws + 12800000);            //      1,024 B
    float* lsum   = (float*)(ws + 12801024);            //      1,024 B
    int*   cnt    = (int*)(ws + 12802048);              //      1,024 B
    int*   idx    = (int*)(ws + 12803072);              //  1,048,576 B
    float* wts    = (float*)(ws + 13851648);            //  1,048,576 B
    u16*   xfh    = (u16*)(ws + 14900224);              //    196,608 B
    u16*   xfl    = (u16*)(ws + 15096832);              //    196,608 B

    k0_split_x_v2<<<48, 256, 0, stream>>>(x, xfh, xfl);
    k1_logits_v6<<<NTRAIN / 32, 256, 0, stream>>>(train, xfh, xfl, alphas, tptr, logits);
    k2a_rowmax<<<BATCH * NSEG, 256, 0, stream>>>(logits, m_part);
    k2b_select<<<BATCH * NSEG, 256, 0, stream>>>(logits, m_part, idx, wts, cnt, lsum);
    k3_gather<<<BATCH * 12, 256, 0, stream>>>(x, train, idx, wts, cnt, lsum,
                                              alphas, tptr, out);
}

// Round 12
// 305.913 us; speedup vs baseline: 1.1935x; 1.0323x over previous
//
#include <hip/hip_runtime.h>

#define BATCH  32
#define DIM    3072
#define NTRAIN 100000
#define NBLK1  3125          /* NTRAIN / 32 */

/* k1 v7: counted-vmcnt pipeline, full-wave swizzled staging */
#define KCH    128           /* k per chunk */
#define NCH    24            /* DIM / KCH */
#define ROWB   512           /* 512 B data, no pad; XOR swizzle for banks */
#define BUFB   (32 * ROWB)   /* 16384 B per buffer; 3 buffers = 49152 B */

/* selection */
#define NSEG   8
#define SEGJ   12500         /* NTRAIN / NSEG */
#define SEGCAP 1024
#define THRESH 25.0f
#define MPROW  3136          /* padded NBLK1 for m_part rows */

typedef __bf16 bf16x8 __attribute__((ext_vector_type(8)));
typedef float  f32x16 __attribute__((ext_vector_type(16)));
typedef unsigned short u16;
typedef unsigned int   u32;

union F8 { u16 us[8]; u32 ui[4]; uint4 u4; bf16x8 bf; };

__device__ __forceinline__ u16   bft(float f){ return (u16)(__float_as_uint(f) >> 16); }
__device__ __forceinline__ float bfh(float f){ return __uint_as_float(__float_as_uint(f) & 0xFFFF0000u); }

// ---------------- K0: split x into bf16 hi/lo, fragment-ordered ----------------
// Layout: [kb16 0..191][row 0..31][g 0..1][8 u16]
__global__ __launch_bounds__(256) void k0_split_x_v2(
        const float* __restrict__ x, u16* __restrict__ xfh, u16* __restrict__ xfl) {
    int task = blockIdx.x * 256 + threadIdx.x;   // 12288 tasks
    if (task >= 12288) return;
    int kb  = task >> 6;
    int rem = task & 63;
    int r   = rem >> 1;
    int g   = rem & 1;
    const float* src = x + r * DIM + kb * 16 + g * 8;
    float4 A = *(const float4*)(src);
    float4 B = *(const float4*)(src + 4);
    float fv[8] = {A.x, A.y, A.z, A.w, B.x, B.y, B.z, B.w};
    F8 h, l;
#pragma unroll
    for (int e = 0; e < 8; ++e) {
        h.us[e] = bft(fv[e]);
        l.us[e] = bft(fv[e] - bfh(fv[e]));
    }
    size_t off = (size_t)kb * 512 + r * 16 + g * 8;
    *(uint4*)(xfh + off) = h.u4;
    *(uint4*)(xfl + off) = l.u4;
}

// ---------------- K1 v7: logits; full-wave swizzled staging + counted vmcnt ----------------
// Stage instr = 64 lanes x 16 B = 1 KB (2 rows), LDS dest linear, source
// pre-swizzled with col ^= (row&7)<<4; reads apply the same XOR (rule #21).
// Per wave per iter: ldx 4 + stage 4 VMEM ops -> steady-state wait = vmcnt(4).
// Epilogue also emits per-block column maxima into m_part (kills k2a's 12.8MB read).
__global__ __launch_bounds__(256) void k1_logits_v7(
        const float* __restrict__ train,
        const u16* __restrict__ xfh, const u16* __restrict__ xfl,
        const float* __restrict__ alphas, const int* __restrict__ tptr,
        float* __restrict__ logits, float* __restrict__ m_part) {
    __shared__ __align__(16) char smem[3 * BUFB];
    const int tid  = threadIdx.x;
    const int lane = tid & 63;
    const int w    = tid >> 6;
    const int l31  = lane & 31;
    const int g    = lane >> 5;
    const int jt0  = blockIdx.x * 32;

    const float ab = alphas[tptr[0]];
    const float s  = sqrtf(ab);
    const float om = 1.0f - ab;
    const float c1 = s / om;
    const float c2 = ab / (2.0f * om);

    const char* gblk = (const char*)train + (size_t)jt0 * (DIM * 4);

    f32x16 acc;
#pragma unroll
    for (int r = 0; r < 16; ++r) acc[r] = 0.0f;
    float tsqp = 0.0f;

    // wave w stages rows w*8 .. w*8+7 of chunk c via 4 full-wave 1KB instrs.
    // LDS[r][col] = train[r][kc + (col ^ ((r&7)<<4))]  (bijective within row)
    auto stage = [&](int buf, int c) {
#pragma unroll
        for (int i = 0; i < 4; ++i) {
            const int R0 = w * 8 + i * 2;
            const int r  = R0 + (lane >> 5);                 // this lane's row
            const u32 colS = (u32)((lane & 31) << 4) ^ ((u32)(r & 7) << 4);
            const char* src = gblk + (size_t)r * (DIM * 4) + c * (KCH * 4) + colS;
            char* dst = smem + buf * BUFB + R0 * ROWB;       // wave-uniform base
            __builtin_amdgcn_global_load_lds(
                (const __attribute__((address_space(1))) unsigned int*)src,
                (__attribute__((address_space(3))) unsigned int*)dst,
                16, 0, 0);
        }
    };
    // x-fragment loads for chunk c: 4 dense 1KB loads per wave
    auto ldx = [&](int c, F8* ah, F8* al) {
#pragma unroll
        for (int s4 = 0; s4 < 2; ++s4) {
            const int kb16 = c * 8 + w * 2 + s4;
            const size_t off = (size_t)kb16 * 512 + l31 * 16 + g * 8;
            ah[s4].u4 = *(const uint4*)(xfh + off);
            al[s4].u4 = *(const uint4*)(xfl + off);
        }
    };

    F8 ahc[2], alc[2];
    // prologue order: stage(0) [4], xfrag(0) [4], stage(1) [4]
    stage(0, 0);
    __builtin_amdgcn_sched_barrier(0);
    ldx(0, ahc, alc);
    __builtin_amdgcn_sched_barrier(0);
    stage(1, 1);

    const u32 rsw = ((u32)(l31 & 7)) << 4;      // read-side swizzle for row l31

    for (int c = 0; c < NCH; ++c) {
        if (c < NCH - 1) {
            asm volatile("s_waitcnt vmcnt(4)\n\ts_barrier" ::: "memory");
        } else {
            asm volatile("s_waitcnt vmcnt(0)\n\ts_barrier" ::: "memory");
        }

        F8 ahn[2], aln[2];
        if (c + 1 < NCH) ldx(c + 1, ahn, aln);      // issued BEFORE next stage
        __builtin_amdgcn_sched_barrier(0);
        if (c + 2 < NCH) stage((c + 2) % 3, c + 2); // buf read at c-1: done
        __builtin_amdgcn_sched_barrier(0);

        const char* lb = smem + (c % 3) * BUFB + l31 * ROWB;
#pragma unroll
        for (int s4 = 0; s4 < 2; ++s4) {
            const u32 kb0 = (u32)(w * 128 + s4 * 64 + g * 32);
            const float4 f0 = *(const float4*)(lb + ((kb0      ) ^ rsw));
            const float4 f1 = *(const float4*)(lb + ((kb0 + 16u) ^ rsw));
            float fv[8] = {f0.x, f0.y, f0.z, f0.w, f1.x, f1.y, f1.z, f1.w};
            F8 bh, bl;
#pragma unroll
            for (int e = 0; e < 8; ++e) {
                float f = fv[e];
                bh.us[e] = bft(f);
                bl.us[e] = bft(f - bfh(f));
                tsqp = fmaf(f, f, tsqp);
            }
            acc = __builtin_amdgcn_mfma_f32_32x32x16_bf16(ahc[s4].bf, bh.bf, acc, 0, 0, 0);
            acc = __builtin_amdgcn_mfma_f32_32x32x16_bf16(alc[s4].bf, bh.bf, acc, 0, 0, 0);
            acc = __builtin_amdgcn_mfma_f32_32x32x16_bf16(ahc[s4].bf, bl.bf, acc, 0, 0, 0);
        }
        if (c + 1 < NCH) {
            ahc[0] = ahn[0]; ahc[1] = ahn[1];
            alc[0] = aln[0]; alc[1] = aln[1];
        }
    }
    __syncthreads();      // all compute done; smem reusable for the reduce

    // ---- cross-wave reduce (acc over k-quarters) + tsq ----
    tsqp += __shfl_xor(tsqp, 32);
    float* red = (float*)smem;
    if (w > 0) {
        float* dp = red + ((w - 1) * 64 + lane) * 16;
#pragma unroll
        for (int r = 0; r < 16; ++r) dp[r] = acc[r];
    }
    if (g == 0) red[3072 + w * 32 + l31] = tsqp;
    __syncthreads();
    if (w == 0) {
#pragma unroll
        for (int q = 0; q < 3; ++q) {
            const float* sp = red + (q * 64 + lane) * 16;
#pragma unroll
            for (int r = 0; r < 16; ++r) acc[r] += sp[r];
        }
        const float tsq = red[3072 + l31] + red[3072 + 32 + l31]
                        + red[3072 + 64 + l31] + red[3072 + 96 + l31];
        float lg[16];
#pragma unroll
        for (int r = 0; r < 16; ++r) {
            lg[r] = c1 * acc[r] - c2 * tsq;
            int brow = (r & 3) + 8 * (r >> 2) + 4 * g;
            logits[(size_t)brow * NTRAIN + jt0 + l31] = lg[r];
        }
        // per-block column max over the 32 j's (butterfly within each 32-lane half)
#pragma unroll
        for (int d = 1; d < 32; d <<= 1)
#pragma unroll
            for (int r = 0; r < 16; ++r)
                lg[r] = fmaxf(lg[r], __shfl_xor(lg[r], d));
        if (l31 == 0) {
#pragma unroll
            for (int r = 0; r < 16; ++r) {
                int brow = (r & 3) + 8 * (r >> 2) + 4 * g;
                m_part[(size_t)brow * MPROW + blockIdx.x] = lg[r];
            }
        }
    }
}

// ---------------- K2a v2: reduce per-block maxima (400 KB, 32 blocks) ----------------
__global__ __launch_bounds__(256) void k2a_rowmax_v2(
        const float* __restrict__ m_part, float* __restrict__ m) {
    const int b = blockIdx.x;
    float mx = -3.0e38f;
    for (int i = threadIdx.x; i < NBLK1; i += 256)
        mx = fmaxf(mx, m_part[(size_t)b * MPROW + i]);
    __shared__ float red[256];
    red[threadIdx.x] = mx;
    __syncthreads();
    for (int off = 128; off > 0; off >>= 1) {
        if (threadIdx.x < (unsigned)off)
            red[threadIdx.x] = fmaxf(red[threadIdx.x], red[threadIdx.x + off]);
        __syncthreads();
    }
    if (threadIdx.x == 0) m[b] = red[0];
}

// ---------------- K2b: deterministic top-weight selection ----------------
__global__ __launch_bounds__(256) void k2b_select(
        const float* __restrict__ logits, const float* __restrict__ m,
        int* __restrict__ idx, float* __restrict__ wts,
        int* __restrict__ cnt, float* __restrict__ lsum) {
    const int b   = blockIdx.x >> 3;
    const int seg = blockIdx.x & 7;
    const int tid = threadIdx.x;
    const float mb = m[b];
    const int j0 = seg * SEGJ;
    const int j1 = min(j0 + SEGJ, NTRAIN);
    const float* lrow = logits + (size_t)b * NTRAIN;

    int mycnt = 0;
    for (int j = j0 + tid; j < j1; j += 256)
        if (lrow[j] >= mb - THRESH) ++mycnt;

    __shared__ int   soff[257];
    __shared__ float ssum[256];
    soff[tid + 1] = mycnt;
    __syncthreads();
    if (tid == 0) {
        soff[0] = 0;
        for (int t = 1; t <= 256; ++t) soff[t] += soff[t - 1];
    }
    __syncthreads();

    int off = soff[tid];
    const int base = (b * NSEG + seg) * SEGCAP;
    float mysum = 0.0f;
    for (int j = j0 + tid; j < j1; j += 256) {
        float lg = lrow[j];
        if (lg >= mb - THRESH) {
            float wv = __expf(lg - mb);
            mysum += wv;
            if (off < SEGCAP) { idx[base + off] = j; wts[base + off] = wv; }
            ++off;
        }
    }
    ssum[tid] = mysum;
    __syncthreads();
    if (tid == 0) {
        float Ls = 0.0f;
        for (int t = 0; t < 256; ++t) Ls += ssum[t];
        lsum[b * NSEG + seg] = Ls;
        cnt[b * NSEG + seg]  = min(soff[256], SEGCAP);
    }
}

// ---------------- K3: gather-PV over selected rows + final output (all f32) ----------------
__global__ __launch_bounds__(256) void k3_gather(
        const float* __restrict__ x, const float* __restrict__ train,
        const int* __restrict__ idx, const float* __restrict__ wts,
        const int* __restrict__ cnt, const float* __restrict__ lsum,
        const float* __restrict__ alphas, const int* __restrict__ tptr,
        float* __restrict__ out) {
    const int blk  = blockIdx.x;       // b*12 + dseg
    const int b    = blk / 12;
    const int dseg = blk % 12;
    const int d    = dseg * 256 + threadIdx.x;

    const float ab  = alphas[tptr[0]];
    const float s   = sqrtf(ab);
    const float om  = 1.0f - ab;
    const float inv = 1.0f / sqrtf(om);

    float L = 0.0f;
#pragma unroll
    for (int sg = 0; sg < NSEG; ++sg) L += lsum[b * NSEG + sg];

    float acc = 0.0f;
    for (int sg = 0; sg < NSEG; ++sg) {
        const int n    = cnt[b * NSEG + sg];
        const int base = (b * NSEG + sg) * SEGCAP;
        for (int i = 0; i < n; ++i) {
            const int   j = idx[base + i];
            const float w = wts[base + i];
            acc = fmaf(w, train[(size_t)j * DIM + d], acc);
        }
    }
    const size_t o = (size_t)b * DIM + d;
    out[o] = inv * x[o] - s * inv * (acc / L);
}

extern "C" void kernel_launch(void* const* d_in, const int* in_sizes, int n_in,
                              void* d_out, int out_size, void* d_ws, size_t ws_size,
                              hipStream_t stream) {
    const float* x      = (const float*)d_in[0];
    const float* train  = (const float*)d_in[1];
    const float* alphas = (const float*)d_in[2];
    const int*   tptr   = (const int*)d_in[3];
    float* out = (float*)d_out;

    char* ws = (char*)d_ws;
    float* logits = (float*)ws;                         // 12,800,000 B
    float* m_part = (float*)(ws + 12800000);            //    401,408 B
    float* m_arr  = (float*)(ws + 13201408);            //        128 B
    float* lsum   = (float*)(ws + 13201536);            //      1,024 B
    int*   cnt    = (int*)(ws + 13202560);              //      1,024 B
    int*   idx    = (int*)(ws + 13203584);              //  1,048,576 B
    float* wts    = (float*)(ws + 14252160);            //  1,048,576 B
    u16*   xfh    = (u16*)(ws + 15300736);              //    196,608 B
    u16*   xfl    = (u16*)(ws + 15497344);              //    196,608 B

    k0_split_x_v2<<<48, 256, 0, stream>>>(x, xfh, xfl);
    k1_logits_v7<<<NBLK1, 256, 0, stream>>>(train, xfh, xfl, alphas, tptr,
                                            logits, m_part);
    k2a_rowmax_v2<<<BATCH, 256, 0, stream>>>(m_part, m_arr);
    k2b_select<<<BATCH * NSEG, 256, 0, stream>>>(logits, m_arr, idx, wts, cnt, lsum);
    k3_gather<<<BATCH * 12, 256, 0, stream>>>(x, train, idx, wts, cnt, lsum,
                                              alphas, tptr, out);
}

// Round 13
// 293.678 us; speedup vs baseline: 1.2432x; 1.0417x over previous
//
#include <hip/hip_runtime.h>

#define BATCH  32
#define DIM    3072
#define NTRAIN 100000
#define NTILE1 3125          /* j-tiles of 32 */
#define NFULL  3072          /* full-k tiles (= 768 slots x 4 rounds exactly) */
#define NREM   53            /* remainder tiles, k-split 4-ways */

/* k1: counted-vmcnt pipeline, full-wave swizzled staging */
#define KCH    128           /* k per chunk */
#define NCH    24            /* chunks, full tile */
#define NCHQ   6             /* chunks, quarter tile */
#define ROWB   512           /* 512 B data, XOR-swizzled banks */
#define BUFB   (32 * ROWB)   /* 16384 B per buffer; 3 buffers */

/* selection */
#define NSEG   8
#define SEGJ   12500
#define SEGCAP 1024
#define THRESH 25.0f
#define MPROW  3136          /* padded NTILE1 for m_part rows */

typedef __bf16 bf16x8 __attribute__((ext_vector_type(8)));
typedef float  f32x16 __attribute__((ext_vector_type(16)));
typedef unsigned short u16;
typedef unsigned int   u32;

union F8 { u16 us[8]; u32 ui[4]; uint4 u4; bf16x8 bf; };

__device__ __forceinline__ u16   bft(float f){ return (u16)(__float_as_uint(f) >> 16); }
__device__ __forceinline__ float bfh(float f){ return __uint_as_float(__float_as_uint(f) & 0xFFFF0000u); }

// ---------------- K0: split x into bf16 hi/lo, fragment-ordered ----------------
__global__ __launch_bounds__(256) void k0_split_x_v2(
        const float* __restrict__ x, u16* __restrict__ xfh, u16* __restrict__ xfl) {
    int task = blockIdx.x * 256 + threadIdx.x;   // 12288 tasks
    if (task >= 12288) return;
    int kb  = task >> 6;
    int rem = task & 63;
    int r   = rem >> 1;
    int g   = rem & 1;
    const float* src = x + r * DIM + kb * 16 + g * 8;
    float4 A = *(const float4*)(src);
    float4 B = *(const float4*)(src + 4);
    float fv[8] = {A.x, A.y, A.z, A.w, B.x, B.y, B.z, B.w};
    F8 h, l;
#pragma unroll
    for (int e = 0; e < 8; ++e) {
        h.us[e] = bft(fv[e]);
        l.us[e] = bft(fv[e] - bfh(fv[e]));
    }
    size_t off = (size_t)kb * 512 + r * 16 + g * 8;
    *(uint4*)(xfh + off) = h.u4;
    *(uint4*)(xfl + off) = l.u4;
}

// ---------------- K1 v8: logits; tail-balanced grid ----------------
// bid < NFULL: full tile (24 chunks). bid >= NFULL: quarter tile
// (tile NFULL + rem/4, k-part rem%4, 6 chunks) -> scaled partials to qpart.
__global__ __launch_bounds__(256) void k1_logits_v8(
        const float* __restrict__ train,
        const u16* __restrict__ xfh, const u16* __restrict__ xfl,
        const float* __restrict__ alphas, const int* __restrict__ tptr,
        float* __restrict__ logits, float* __restrict__ m_part,
        float* __restrict__ qpart) {
    __shared__ __align__(16) char smem[3 * BUFB];
    const int tid  = threadIdx.x;
    const int lane = tid & 63;
    const int w    = tid >> 6;
    const int l31  = lane & 31;
    const int g    = lane >> 5;
    const int bid  = blockIdx.x;

    int tile, cbase, nch, qp = 0;
    if (bid < NFULL) { tile = bid; cbase = 0; nch = NCH; }
    else {
        int rem = bid - NFULL;
        tile  = NFULL + (rem >> 2);
        qp    = rem & 3;
        cbase = qp * NCHQ;
        nch   = NCHQ;
    }
    const int jt0 = tile * 32;

    const float ab = alphas[tptr[0]];
    const float s  = sqrtf(ab);
    const float om = 1.0f - ab;
    const float c1 = s / om;
    const float c2 = ab / (2.0f * om);

    const char* gblk = (const char*)train + (size_t)jt0 * (DIM * 4);

    f32x16 acc;
#pragma unroll
    for (int r = 0; r < 16; ++r) acc[r] = 0.0f;
    float tsqp = 0.0f;

    // stage chunk c (absolute) into buffer buf: 4 full-wave 1KB instrs/wave,
    // source pre-swizzled col ^= (row&7)<<4, LDS dest linear (rule #21).
    auto stage = [&](int buf, int c) {
#pragma unroll
        for (int i = 0; i < 4; ++i) {
            const int R0 = w * 8 + i * 2;
            const int r  = R0 + (lane >> 5);
            const u32 colS = (u32)((lane & 31) << 4) ^ ((u32)(r & 7) << 4);
            const char* src = gblk + (size_t)r * (DIM * 4) + c * (KCH * 4) + colS;
            char* dst = smem + buf * BUFB + R0 * ROWB;
            __builtin_amdgcn_global_load_lds(
                (const __attribute__((address_space(1))) unsigned int*)src,
                (__attribute__((address_space(3))) unsigned int*)dst,
                16, 0, 0);
        }
    };
    auto ldx = [&](int c, F8* ah, F8* al) {
#pragma unroll
        for (int s4 = 0; s4 < 2; ++s4) {
            const int kb16 = c * 8 + w * 2 + s4;
            const size_t off = (size_t)kb16 * 512 + l31 * 16 + g * 8;
            ah[s4].u4 = *(const uint4*)(xfh + off);
            al[s4].u4 = *(const uint4*)(xfl + off);
        }
    };

    F8 ahc[2], alc[2];
    stage(0, cbase);
    __builtin_amdgcn_sched_barrier(0);
    ldx(cbase, ahc, alc);
    __builtin_amdgcn_sched_barrier(0);
    stage(1, cbase + 1);

    const u32 rsw = ((u32)(l31 & 7)) << 4;

    for (int i = 0; i < nch; ++i) {
        if (i < nch - 1) {
            asm volatile("s_waitcnt vmcnt(4)\n\ts_barrier" ::: "memory");
        } else {
            asm volatile("s_waitcnt vmcnt(0)\n\ts_barrier" ::: "memory");
        }

        F8 ahn[2], aln[2];
        if (i + 1 < nch) ldx(cbase + i + 1, ahn, aln);
        __builtin_amdgcn_sched_barrier(0);
        if (i + 2 < nch) stage((i + 2) % 3, cbase + i + 2);
        __builtin_amdgcn_sched_barrier(0);

        const char* lb = smem + (i % 3) * BUFB + l31 * ROWB;
#pragma unroll
        for (int s4 = 0; s4 < 2; ++s4) {
            const u32 kb0 = (u32)(w * 128 + s4 * 64 + g * 32);
            const float4 f0 = *(const float4*)(lb + ((kb0      ) ^ rsw));
            const float4 f1 = *(const float4*)(lb + ((kb0 + 16u) ^ rsw));
            float fv[8] = {f0.x, f0.y, f0.z, f0.w, f1.x, f1.y, f1.z, f1.w};
            F8 bh, bl;
#pragma unroll
            for (int e = 0; e < 8; ++e) {
                float f = fv[e];
                bh.us[e] = bft(f);
                bl.us[e] = bft(f - bfh(f));
                tsqp = fmaf(f, f, tsqp);
            }
            acc = __builtin_amdgcn_mfma_f32_32x32x16_bf16(ahc[s4].bf, bh.bf, acc, 0, 0, 0);
            acc = __builtin_amdgcn_mfma_f32_32x32x16_bf16(alc[s4].bf, bh.bf, acc, 0, 0, 0);
            acc = __builtin_amdgcn_mfma_f32_32x32x16_bf16(ahc[s4].bf, bl.bf, acc, 0, 0, 0);
        }
        if (i + 1 < nch) {
            ahc[0] = ahn[0]; ahc[1] = ahn[1];
            alc[0] = aln[0]; alc[1] = aln[1];
        }
    }
    __syncthreads();      // all compute done; smem reusable for the reduce

    // ---- cross-wave reduce (acc over k-quarters) + tsq ----
    tsqp += __shfl_xor(tsqp, 32);
    float* red = (float*)smem;
    if (w > 0) {
        float* dp = red + ((w - 1) * 64 + lane) * 16;
#pragma unroll
        for (int r = 0; r < 16; ++r) dp[r] = acc[r];
    }
    if (g == 0) red[3072 + w * 32 + l31] = tsqp;
    __syncthreads();
    if (w == 0) {
#pragma unroll
        for (int q = 0; q < 3; ++q) {
            const float* sp = red + (q * 64 + lane) * 16;
#pragma unroll
            for (int r = 0; r < 16; ++r) acc[r] += sp[r];
        }
        const float tsq = red[3072 + l31] + red[3072 + 32 + l31]
                        + red[3072 + 64 + l31] + red[3072 + 96 + l31];
        if (bid < NFULL) {
            float lg[16];
#pragma unroll
            for (int r = 0; r < 16; ++r) {
                lg[r] = c1 * acc[r] - c2 * tsq;
                int brow = (r & 3) + 8 * (r >> 2) + 4 * g;
                logits[(size_t)brow * NTRAIN + jt0 + l31] = lg[r];
            }
#pragma unroll
            for (int d = 1; d < 32; d <<= 1)
#pragma unroll
                for (int r = 0; r < 16; ++r)
                    lg[r] = fmaxf(lg[r], __shfl_xor(lg[r], d));
            if (l31 == 0) {
#pragma unroll
                for (int r = 0; r < 16; ++r) {
                    int brow = (r & 3) + 8 * (r >> 2) + 4 * g;
                    m_part[(size_t)brow * MPROW + bid] = lg[r];
                }
            }
        } else {
            const int t = tile - NFULL;
#pragma unroll
            for (int r = 0; r < 16; ++r) {
                int brow = (r & 3) + 8 * (r >> 2) + 4 * g;
                qpart[(((size_t)t * 4 + qp) * 32 + brow) * 32 + l31]
                    = c1 * acc[r] - c2 * tsq;
            }
        }
    }
}

// ---------------- K1c: combine quarter partials -> logits + m_part ----------------
__global__ __launch_bounds__(256) void k1c_combine(
        const float* __restrict__ qpart, float* __restrict__ logits,
        float* __restrict__ m_part) {
    const int t    = blockIdx.x;        // 0..NREM-1
    const int brow = threadIdx.x >> 3;  // 0..31
    const int jg   = threadIdx.x & 7;   // 4 j's each
    float v[4];
    float mx = -3.0e38f;
#pragma unroll
    for (int jj = 0; jj < 4; ++jj) {
        const int j31 = jg * 4 + jj;
        float sum = 0.0f;
#pragma unroll
        for (int p = 0; p < 4; ++p)
            sum += qpart[(((size_t)t * 4 + p) * 32 + brow) * 32 + j31];
        v[jj] = sum;
        mx = fmaxf(mx, sum);
    }
    *(float4*)(logits + (size_t)brow * NTRAIN + NFULL * 32 + t * 32 + jg * 4)
        = make_float4(v[0], v[1], v[2], v[3]);
    mx = fmaxf(mx, __shfl_xor(mx, 1));
    mx = fmaxf(mx, __shfl_xor(mx, 2));
    mx = fmaxf(mx, __shfl_xor(mx, 4));
    if (jg == 0) m_part[(size_t)brow * MPROW + NFULL + t] = mx;
}

// ---------------- K2b: inline row-max + deterministic top-weight selection ----------------
__global__ __launch_bounds__(256) void k2b_select(
        const float* __restrict__ logits, const float* __restrict__ m_part,
        int* __restrict__ idx, float* __restrict__ wts,
        int* __restrict__ cnt, float* __restrict__ lsum) {
    const int b   = blockIdx.x >> 3;
    const int seg = blockIdx.x & 7;
    const int tid = threadIdx.x;

    __shared__ int   soff[257];
    __shared__ float ssum[256];

    // global row max from per-tile maxima (12.5 KB)
    float mx = -3.0e38f;
    for (int i = tid; i < NTILE1; i += 256)
        mx = fmaxf(mx, m_part[(size_t)b * MPROW + i]);
    ssum[tid] = mx;
    __syncthreads();
    for (int off = 128; off > 0; off >>= 1) {
        if (tid < off) ssum[tid] = fmaxf(ssum[tid], ssum[tid + off]);
        __syncthreads();
    }
    const float mb = ssum[0];
    __syncthreads();

    const int j0 = seg * SEGJ;
    const int j1 = min(j0 + SEGJ, NTRAIN);
    const float* lrow = logits + (size_t)b * NTRAIN;

    int mycnt = 0;
    for (int j = j0 + tid; j < j1; j += 256)
        if (lrow[j] >= mb - THRESH) ++mycnt;

    soff[tid + 1] = mycnt;
    __syncthreads();
    if (tid == 0) {
        soff[0] = 0;
        for (int t = 1; t <= 256; ++t) soff[t] += soff[t - 1];
    }
    __syncthreads();

    int off = soff[tid];
    const int base = (b * NSEG + seg) * SEGCAP;
    float mysum = 0.0f;
    for (int j = j0 + tid; j < j1; j += 256) {
        float lg = lrow[j];
        if (lg >= mb - THRESH) {
            float wv = __expf(lg - mb);
            mysum += wv;
            if (off < SEGCAP) { idx[base + off] = j; wts[base + off] = wv; }
            ++off;
        }
    }
    ssum[tid] = mysum;
    __syncthreads();
    for (int o2 = 128; o2 > 0; o2 >>= 1) {
        if (tid < o2) ssum[tid] += ssum[tid + o2];
        __syncthreads();
    }
    if (tid == 0) {
        lsum[b * NSEG + seg] = ssum[0];
        cnt[b * NSEG + seg]  = min(soff[256], SEGCAP);
    }
}

// ---------------- K3: gather-PV over selected rows + final output (all f32) ----------------
__global__ __launch_bounds__(256) void k3_gather(
        const float* __restrict__ x, const float* __restrict__ train,
        const int* __restrict__ idx, const float* __restrict__ wts,
        const int* __restrict__ cnt, const float* __restrict__ lsum,
        const float* __restrict__ alphas, const int* __restrict__ tptr,
        float* __restrict__ out) {
    const int blk  = blockIdx.x;       // b*12 + dseg
    const int b    = blk / 12;
    const int dseg = blk % 12;
    const int d    = dseg * 256 + threadIdx.x;

    const float ab  = alphas[tptr[0]];
    const float s   = sqrtf(ab);
    const float om  = 1.0f - ab;
    const float inv = 1.0f / sqrtf(om);

    float L = 0.0f;
#pragma unroll
    for (int sg = 0; sg < NSEG; ++sg) L += lsum[b * NSEG + sg];

    float acc = 0.0f;
    for (int sg = 0; sg < NSEG; ++sg) {
        const int n    = cnt[b * NSEG + sg];
        const int base = (b * NSEG + sg) * SEGCAP;
        for (int i = 0; i < n; ++i) {
            const int   j = idx[base + i];
            const float w = wts[base + i];
            acc = fmaf(w, train[(size_t)j * DIM + d], acc);
        }
    }
    const size_t o = (size_t)b * DIM + d;
    out[o] = inv * x[o] - s * inv * (acc / L);
}

extern "C" void kernel_launch(void* const* d_in, const int* in_sizes, int n_in,
                              void* d_out, int out_size, void* d_ws, size_t ws_size,
                              hipStream_t stream) {
    const float* x      = (const float*)d_in[0];
    const float* train  = (const float*)d_in[1];
    const float* alphas = (const float*)d_in[2];
    const int*   tptr   = (const int*)d_in[3];
    float* out = (float*)d_out;

    char* ws = (char*)d_ws;
    float* logits = (float*)ws;                         // 12,800,000 B
    float* m_part = (float*)(ws + 12800000);            //    401,408 B
    float* qpart  = (float*)(ws + 13201408);            //    868,352 B
    float* lsum   = (float*)(ws + 14069760);            //      1,024 B
    int*   cnt    = (int*)(ws + 14070784);              //      1,024 B
    int*   idx    = (int*)(ws + 14071808);              //  1,048,576 B
    float* wts    = (float*)(ws + 15120384);            //  1,048,576 B
    u16*   xfh    = (u16*)(ws + 16168960);              //    196,608 B
    u16*   xfl    = (u16*)(ws + 16365568);              //    196,608 B

    k0_split_x_v2<<<48, 256, 0, stream>>>(x, xfh, xfl);
    k1_logits_v8<<<NFULL + NREM * 4, 256, 0, stream>>>(train, xfh, xfl, alphas,
                                                       tptr, logits, m_part, qpart);
    k1c_combine<<<NREM, 256, 0, stream>>>(qpart, logits, m_part);
    k2b_select<<<BATCH * NSEG, 256, 0, stream>>>(logits, m_part, idx, wts, cnt, lsum);
    k3_gather<<<BATCH * 12, 256, 0, stream>>>(x, train, idx, wts, cnt, lsum,
                                              alphas, tptr, out);
}

// Round 14
// 267.344 us; speedup vs baseline: 1.3656x; 1.0985x over previous
//
#include <hip/hip_runtime.h>

#define BATCH  32
#define DIM    3072
#define NTRAIN 100000
#define NTILE1 3125          /* j-tiles of 32 */
#define NFULL  3072          /* full-k tiles (= 512 slots x 6 rounds exactly) */
#define NREM   53            /* remainder tiles, k-split 4-ways */
#define NF32   98304         /* NFULL*32 */
#define NTAIL  1696          /* NTRAIN - NF32 */

/* k1 v9: 1KB-granule staging, double buffer */
#define KCH    256           /* k per chunk */
#define NCH    12            /* chunks, full tile */
#define NCHQ   3             /* chunks, quarter tile */
#define ROWB   1024          /* bytes per row per chunk */
#define BUFB   (32 * ROWB)   /* 32768 B per buffer; 2 buffers = 64 KB */

/* selection */
#define NSEG   8
#define SEGJ   12500
#define SEGCAP 1024
#define THRESH 25.0f

typedef __bf16 bf16x8 __attribute__((ext_vector_type(8)));
typedef float  f32x16 __attribute__((ext_vector_type(16)));
typedef unsigned short u16;
typedef unsigned int   u32;

union F8 { u16 us[8]; u32 ui[4]; uint4 u4; bf16x8 bf; };

__device__ __forceinline__ u16   bft(float f){ return (u16)(__float_as_uint(f) >> 16); }
__device__ __forceinline__ float bfh(float f){ return __uint_as_float(__float_as_uint(f) & 0xFFFF0000u); }

// ---------------- K0: split x into bf16 hi/lo, fragment-ordered ----------------
__global__ __launch_bounds__(256) void k0_split_x_v2(
        const float* __restrict__ x, u16* __restrict__ xfh, u16* __restrict__ xfl) {
    int task = blockIdx.x * 256 + threadIdx.x;   // 12288 tasks
    if (task >= 12288) return;
    int kb  = task >> 6;
    int rem = task & 63;
    int r   = rem >> 1;
    int g   = rem & 1;
    const float* src = x + r * DIM + kb * 16 + g * 8;
    float4 A = *(const float4*)(src);
    float4 B = *(const float4*)(src + 4);
    float fv[8] = {A.x, A.y, A.z, A.w, B.x, B.y, B.z, B.w};
    F8 h, l;
#pragma unroll
    for (int e = 0; e < 8; ++e) {
        h.us[e] = bft(fv[e]);
        l.us[e] = bft(fv[e] - bfh(fv[e]));
    }
    size_t off = (size_t)kb * 512 + r * 16 + g * 8;
    *(uint4*)(xfh + off) = h.u4;
    *(uint4*)(xfl + off) = l.u4;
}

// ---------------- K1 v9: logits; 1KB staging granule, double buffer ----------------
// bid < NFULL: full tile (12 chunks). bid >= NFULL: quarter tile (3 chunks)
// -> scaled partials to qpart. Chunk period >> HBM latency -> depth-1
// prefetch with __syncthreads drain is throughput-optimal.
__global__ __launch_bounds__(256) void k1_logits_v9(
        const float* __restrict__ train,
        const u16* __restrict__ xfh, const u16* __restrict__ xfl,
        const float* __restrict__ alphas, const int* __restrict__ tptr,
        float* __restrict__ logits, float* __restrict__ m_part,
        float* __restrict__ qpart) {
    __shared__ __align__(16) char smem[2 * BUFB];
    const int tid  = threadIdx.x;
    const int lane = tid & 63;
    const int w    = tid >> 6;
    const int l31  = lane & 31;
    const int g    = lane >> 5;
    const int bid  = blockIdx.x;

    int tile, cbase, nch, qp = 0;
    if (bid < NFULL) { tile = bid; cbase = 0; nch = NCH; }
    else {
        int rem = bid - NFULL;
        tile  = NFULL + (rem >> 2);
        qp    = rem & 3;
        cbase = qp * NCHQ;
        nch   = NCHQ;
    }
    const int jt0 = tile * 32;

    const float ab = alphas[tptr[0]];
    const float s  = sqrtf(ab);
    const float om = 1.0f - ab;
    const float c1 = s / om;
    const float c2 = ab / (2.0f * om);

    const char* gblk = (const char*)train + (size_t)jt0 * (DIM * 4);

    f32x16 acc;
#pragma unroll
    for (int r = 0; r < 16; ++r) acc[r] = 0.0f;
    float tsqp = 0.0f;

    // stage chunk c into buffer buf: 8 full-wave 1KB instrs/wave (one row each),
    // source pre-swizzled col ^= (row&7)<<4, LDS dest linear (rule #21).
    auto stage = [&](int buf, int c) {
#pragma unroll
        for (int i = 0; i < 8; ++i) {
            const int r = w * 8 + i;
            const u32 colS = (u32)(lane << 4) ^ ((u32)(r & 7) << 4);
            const char* src = gblk + (size_t)r * (DIM * 4) + c * (KCH * 4) + colS;
            char* dst = smem + buf * BUFB + r * ROWB;
            __builtin_amdgcn_global_load_lds(
                (const __attribute__((address_space(1))) unsigned int*)src,
                (__attribute__((address_space(3))) unsigned int*)dst,
                16, 0, 0);
        }
    };
    // x-fragment loads for chunk c: 8 dense 1KB loads per wave
    auto ldx = [&](int c, F8* ah, F8* al) {
#pragma unroll
        for (int s4 = 0; s4 < 4; ++s4) {
            const int kb16 = c * 16 + w * 4 + s4;
            const size_t off = (size_t)kb16 * 512 + l31 * 16 + g * 8;
            ah[s4].u4 = *(const uint4*)(xfh + off);
            al[s4].u4 = *(const uint4*)(xfl + off);
        }
    };

    F8 ahc[4], alc[4];
    ldx(cbase, ahc, alc);
    __builtin_amdgcn_sched_barrier(0);
    stage(0, cbase);
    __builtin_amdgcn_sched_barrier(0);

    const u32 rsw = ((u32)(l31 & 7)) << 4;

    for (int i = 0; i < nch; ++i) {
        __syncthreads();           // drains vmcnt: stage(i)+ldx(i) landed; buf swap safe

        F8 ahn[4], aln[4];
        if (i + 1 < nch) {
            ldx(cbase + i + 1, ahn, aln);
            __builtin_amdgcn_sched_barrier(0);
            stage((i + 1) & 1, cbase + i + 1);
            __builtin_amdgcn_sched_barrier(0);
        }

        const char* lb = smem + (i & 1) * BUFB + l31 * ROWB;
#pragma unroll
        for (int s4 = 0; s4 < 4; ++s4) {
            const u32 kb0 = (u32)(w * 256 + s4 * 64 + g * 32);
            const float4 f0 = *(const float4*)(lb + ((kb0      ) ^ rsw));
            const float4 f1 = *(const float4*)(lb + ((kb0 + 16u) ^ rsw));
            float fv[8] = {f0.x, f0.y, f0.z, f0.w, f1.x, f1.y, f1.z, f1.w};
            F8 bh, bl;
#pragma unroll
            for (int e = 0; e < 8; ++e) {
                float f = fv[e];
                bh.us[e] = bft(f);
                bl.us[e] = bft(f - bfh(f));
                tsqp = fmaf(f, f, tsqp);
            }
            acc = __builtin_amdgcn_mfma_f32_32x32x16_bf16(ahc[s4].bf, bh.bf, acc, 0, 0, 0);
            acc = __builtin_amdgcn_mfma_f32_32x32x16_bf16(alc[s4].bf, bh.bf, acc, 0, 0, 0);
            acc = __builtin_amdgcn_mfma_f32_32x32x16_bf16(ahc[s4].bf, bl.bf, acc, 0, 0, 0);
        }
        if (i + 1 < nch) {
#pragma unroll
            for (int s4 = 0; s4 < 4; ++s4) { ahc[s4] = ahn[s4]; alc[s4] = aln[s4]; }
        }
    }
    __syncthreads();      // all compute done; smem reusable for the reduce

    // ---- cross-wave reduce (acc over k-quarters) + tsq ----
    tsqp += __shfl_xor(tsqp, 32);
    float* red = (float*)smem;
    if (w > 0) {
        float* dp = red + ((w - 1) * 64 + lane) * 16;
#pragma unroll
        for (int r = 0; r < 16; ++r) dp[r] = acc[r];
    }
    if (g == 0) red[3072 + w * 32 + l31] = tsqp;
    __syncthreads();
    if (w == 0) {
#pragma unroll
        for (int q = 0; q < 3; ++q) {
            const float* sp = red + (q * 64 + lane) * 16;
#pragma unroll
            for (int r = 0; r < 16; ++r) acc[r] += sp[r];
        }
        const float tsq = red[3072 + l31] + red[3072 + 32 + l31]
                        + red[3072 + 64 + l31] + red[3072 + 96 + l31];
        if (bid < NFULL) {
            float lg[16];
#pragma unroll
            for (int r = 0; r < 16; ++r) {
                lg[r] = c1 * acc[r] - c2 * tsq;
                int brow = (r & 3) + 8 * (r >> 2) + 4 * g;
                logits[(size_t)brow * NF32 + jt0 + l31] = lg[r];
            }
#pragma unroll
            for (int d = 1; d < 32; d <<= 1)
#pragma unroll
                for (int r = 0; r < 16; ++r)
                    lg[r] = fmaxf(lg[r], __shfl_xor(lg[r], d));
            if (l31 == 0) {
#pragma unroll
                for (int r = 0; r < 16; ++r) {
                    int brow = (r & 3) + 8 * (r >> 2) + 4 * g;
                    m_part[(size_t)brow * NFULL + bid] = lg[r];
                }
            }
        } else {
            const int t = tile - NFULL;
#pragma unroll
            for (int r = 0; r < 16; ++r) {
                int brow = (r & 3) + 8 * (r >> 2) + 4 * g;
                qpart[(((size_t)t * 4 + qp) * 32 + brow) * 32 + l31]
                    = c1 * acc[r] - c2 * tsq;
            }
        }
    }
}

// ---------------- K2b: row-max + tail-combine + deterministic selection ----------------
// mb = max over FULL tiles only (tail can exceed by ~EV spacing ~2; weights
// e^2 safe in f32; L renormalizes). seg==7 combines the 53 tail tiles' qpart
// into LDS and selects from there — k1c kernel eliminated.
__global__ __launch_bounds__(256) void k2b_select(
        const float* __restrict__ logits, const float* __restrict__ m_part,
        const float* __restrict__ qpart,
        int* __restrict__ idx, float* __restrict__ wts,
        int* __restrict__ cnt, float* __restrict__ lsum) {
    const int b   = blockIdx.x >> 3;
    const int seg = blockIdx.x & 7;
    const int tid = threadIdx.x;

    __shared__ float tail_lg[NTAIL];
    __shared__ int   soff[257];
    __shared__ float ssum[256];

    // global row max from per-tile maxima (12 KB)
    float mx = -3.0e38f;
    for (int i = tid; i < NFULL; i += 256)
        mx = fmaxf(mx, m_part[(size_t)b * NFULL + i]);
    ssum[tid] = mx;
    __syncthreads();
    for (int off = 128; off > 0; off >>= 1) {
        if (tid < off) ssum[tid] = fmaxf(ssum[tid], ssum[tid + off]);
        __syncthreads();
    }
    const float mb = ssum[0];
    __syncthreads();

    if (seg == 7) {
        for (int u = tid; u < NTAIL; u += 256) {
            const int t = u >> 5, j31 = u & 31;
            float sum = 0.0f;
#pragma unroll
            for (int p = 0; p < 4; ++p)
                sum += qpart[(((size_t)t * 4 + p) * 32 + b) * 32 + j31];
            tail_lg[u] = sum;
        }
        __syncthreads();
    }

    const int j0 = seg * SEGJ;
    const int j1 = (seg == 7) ? NTRAIN : (j0 + SEGJ);
    const float* lrow = logits + (size_t)b * NF32;

    auto getlg = [&](int j) -> float {
        return (j < NF32) ? lrow[j] : tail_lg[j - NF32];
    };

    int mycnt = 0;
    for (int j = j0 + tid; j < j1; j += 256)
        if (getlg(j) >= mb - THRESH) ++mycnt;

    soff[tid + 1] = mycnt;
    __syncthreads();
    if (tid == 0) {
        soff[0] = 0;
        for (int t = 1; t <= 256; ++t) soff[t] += soff[t - 1];
    }
    __syncthreads();

    int off = soff[tid];
    const int base = (b * NSEG + seg) * SEGCAP;
    float mysum = 0.0f;
    for (int j = j0 + tid; j < j1; j += 256) {
        float lg = getlg(j);
        if (lg >= mb - THRESH) {
            float wv = __expf(lg - mb);
            mysum += wv;
            if (off < SEGCAP) { idx[base + off] = j; wts[base + off] = wv; }
            ++off;
        }
    }
    ssum[tid] = mysum;
    __syncthreads();
    for (int o2 = 128; o2 > 0; o2 >>= 1) {
        if (tid < o2) ssum[tid] += ssum[tid + o2];
        __syncthreads();
    }
    if (tid == 0) {
        lsum[b * NSEG + seg] = ssum[0];
        cnt[b * NSEG + seg]  = min(soff[256], SEGCAP);
    }
}

// ---------------- K3: gather-PV over selected rows + final output (all f32) ----------------
__global__ __launch_bounds__(256) void k3_gather(
        const float* __restrict__ x, const float* __restrict__ train,
        const int* __restrict__ idx, const float* __restrict__ wts,
        const int* __restrict__ cnt, const float* __restrict__ lsum,
        const float* __restrict__ alphas, const int* __restrict__ tptr,
        float* __restrict__ out) {
    const int blk  = blockIdx.x;       // b*12 + dseg
    const int b    = blk / 12;
    const int dseg = blk % 12;
    const int d    = dseg * 256 + threadIdx.x;

    const float ab  = alphas[tptr[0]];
    const float s   = sqrtf(ab);
    const float om  = 1.0f - ab;
    const float inv = 1.0f / sqrtf(om);

    float L = 0.0f;
#pragma unroll
    for (int sg = 0; sg < NSEG; ++sg) L += lsum[b * NSEG + sg];

    float acc = 0.0f;
    for (int sg = 0; sg < NSEG; ++sg) {
        const int n    = cnt[b * NSEG + sg];
        const int base = (b * NSEG + sg) * SEGCAP;
        for (int i = 0; i < n; ++i) {
            const int   j = idx[base + i];
            const float w = wts[base + i];
            acc = fmaf(w, train[(size_t)j * DIM + d], acc);
        }
    }
    const size_t o = (size_t)b * DIM + d;
    out[o] = inv * x[o] - s * inv * (acc / L);
}

extern "C" void kernel_launch(void* const* d_in, const int* in_sizes, int n_in,
                              void* d_out, int out_size, void* d_ws, size_t ws_size,
                              hipStream_t stream) {
    const float* x      = (const float*)d_in[0];
    const float* train  = (const float*)d_in[1];
    const float* alphas = (const float*)d_in[2];
    const int*   tptr   = (const int*)d_in[3];
    float* out = (float*)d_out;

    char* ws = (char*)d_ws;
    float* logits = (float*)ws;                         // 12,582,912 B
    float* m_part = (float*)(ws + 12582912);            //    393,216 B
    float* qpart  = (float*)(ws + 12976128);            //    868,352 B
    float* lsum   = (float*)(ws + 13844480);            //      1,024 B
    int*   cnt    = (int*)(ws + 13845504);              //      1,024 B
    int*   idx    = (int*)(ws + 13846528);              //  1,048,576 B
    float* wts    = (float*)(ws + 14895104);            //  1,048,576 B
    u16*   xfh    = (u16*)(ws + 15943680);              //    196,608 B
    u16*   xfl    = (u16*)(ws + 16140288);              //    196,608 B

    k0_split_x_v2<<<48, 256, 0, stream>>>(x, xfh, xfl);
    k1_logits_v9<<<NFULL + NREM * 4, 256, 0, stream>>>(train, xfh, xfl, alphas,
                                                       tptr, logits, m_part, qpart);
    k2b_select<<<BATCH * NSEG, 256, 0, stream>>>(logits, m_part, qpart,
                                                 idx, wts, cnt, lsum);
    k3_gather<<<BATCH * 12, 256, 0, stream>>>(x, train, idx, wts, cnt, lsum,
                                              alphas, tptr, out);
}

// Round 15
// 266.936 us; speedup vs baseline: 1.3677x; 1.0015x over previous
//
#include <hip/hip_runtime.h>

#define BATCH  32
#define DIM    3072
#define NTRAIN 100000
#define NTILE1 3125          /* j-tiles of 32 */
#define NFULL  3072          /* full-k tiles (= 512 slots x 6 rounds exactly) */
#define NREM   53            /* remainder tiles, k-split 4-ways */
#define NF32   98304         /* NFULL*32 */
#define NTAIL  1696          /* NTRAIN - NF32 */

/* k1 v9: 1KB-granule staging, double buffer */
#define KCH    256           /* k per chunk */
#define NCH    12            /* chunks, full tile */
#define NCHQ   3             /* chunks, quarter tile */
#define ROWB   1024          /* bytes per row per chunk */
#define BUFB   (32 * ROWB)   /* 32768 B per buffer; 2 buffers = 64 KB */

/* selection */
#define NSEG   8
#define SEGJ   12500
#define SEGCAP 1024
#define THRESH 25.0f

typedef __bf16 bf16x8 __attribute__((ext_vector_type(8)));
typedef float  f32x16 __attribute__((ext_vector_type(16)));
typedef unsigned short u16;
typedef unsigned int   u32;

union F8 { u16 us[8]; u32 ui[4]; uint4 u4; bf16x8 bf; };

__device__ __forceinline__ u16   bft(float f){ return (u16)(__float_as_uint(f) >> 16); }
__device__ __forceinline__ float bfh(float f){ return __uint_as_float(__float_as_uint(f) & 0xFFFF0000u); }

// ---------------- K0: split x into bf16 hi/lo, fragment-ordered ----------------
__global__ __launch_bounds__(256) void k0_split_x_v2(
        const float* __restrict__ x, u16* __restrict__ xfh, u16* __restrict__ xfl) {
    int task = blockIdx.x * 256 + threadIdx.x;   // 12288 tasks
    if (task >= 12288) return;
    int kb  = task >> 6;
    int rem = task & 63;
    int r   = rem >> 1;
    int g   = rem & 1;
    const float* src = x + r * DIM + kb * 16 + g * 8;
    float4 A = *(const float4*)(src);
    float4 B = *(const float4*)(src + 4);
    float fv[8] = {A.x, A.y, A.z, A.w, B.x, B.y, B.z, B.w};
    F8 h, l;
#pragma unroll
    for (int e = 0; e < 8; ++e) {
        h.us[e] = bft(fv[e]);
        l.us[e] = bft(fv[e] - bfh(fv[e]));
    }
    size_t off = (size_t)kb * 512 + r * 16 + g * 8;
    *(uint4*)(xfh + off) = h.u4;
    *(uint4*)(xfl + off) = l.u4;
}

// ---------------- K1 v9: logits; 1KB staging granule, double buffer ----------------
// bid < NFULL: full tile (12 chunks). bid >= NFULL: quarter tile (3 chunks)
// -> scaled partials to qpart. Chunk period >> HBM latency -> depth-1
// prefetch with __syncthreads drain is throughput-optimal.
__global__ __launch_bounds__(256) void k1_logits_v9(
        const float* __restrict__ train,
        const u16* __restrict__ xfh, const u16* __restrict__ xfl,
        const float* __restrict__ alphas, const int* __restrict__ tptr,
        float* __restrict__ logits, float* __restrict__ m_part,
        float* __restrict__ qpart) {
    __shared__ __align__(16) char smem[2 * BUFB];
    const int tid  = threadIdx.x;
    const int lane = tid & 63;
    const int w    = tid >> 6;
    const int l31  = lane & 31;
    const int g    = lane >> 5;
    const int bid  = blockIdx.x;

    int tile, cbase, nch, qp = 0;
    if (bid < NFULL) { tile = bid; cbase = 0; nch = NCH; }
    else {
        int rem = bid - NFULL;
        tile  = NFULL + (rem >> 2);
        qp    = rem & 3;
        cbase = qp * NCHQ;
        nch   = NCHQ;
    }
    const int jt0 = tile * 32;

    const float ab = alphas[tptr[0]];
    const float s  = sqrtf(ab);
    const float om = 1.0f - ab;
    const float c1 = s / om;
    const float c2 = ab / (2.0f * om);

    const char* gblk = (const char*)train + (size_t)jt0 * (DIM * 4);

    f32x16 acc;
#pragma unroll
    for (int r = 0; r < 16; ++r) acc[r] = 0.0f;
    float tsqp = 0.0f;

    // stage chunk c into buffer buf: 8 full-wave 1KB instrs/wave (one row each),
    // source pre-swizzled col ^= (row&7)<<4, LDS dest linear (rule #21).
    auto stage = [&](int buf, int c) {
#pragma unroll
        for (int i = 0; i < 8; ++i) {
            const int r = w * 8 + i;
            const u32 colS = (u32)(lane << 4) ^ ((u32)(r & 7) << 4);
            const char* src = gblk + (size_t)r * (DIM * 4) + c * (KCH * 4) + colS;
            char* dst = smem + buf * BUFB + r * ROWB;
            __builtin_amdgcn_global_load_lds(
                (const __attribute__((address_space(1))) unsigned int*)src,
                (__attribute__((address_space(3))) unsigned int*)dst,
                16, 0, 0);
        }
    };
    // x-fragment loads for chunk c: 8 dense 1KB loads per wave
    auto ldx = [&](int c, F8* ah, F8* al) {
#pragma unroll
        for (int s4 = 0; s4 < 4; ++s4) {
            const int kb16 = c * 16 + w * 4 + s4;
            const size_t off = (size_t)kb16 * 512 + l31 * 16 + g * 8;
            ah[s4].u4 = *(const uint4*)(xfh + off);
            al[s4].u4 = *(const uint4*)(xfl + off);
        }
    };

    F8 ahc[4], alc[4];
    ldx(cbase, ahc, alc);
    __builtin_amdgcn_sched_barrier(0);
    stage(0, cbase);
    __builtin_amdgcn_sched_barrier(0);

    const u32 rsw = ((u32)(l31 & 7)) << 4;

    for (int i = 0; i < nch; ++i) {
        __syncthreads();           // drains vmcnt: stage(i)+ldx(i) landed; buf swap safe

        F8 ahn[4], aln[4];
        if (i + 1 < nch) {
            ldx(cbase + i + 1, ahn, aln);
            __builtin_amdgcn_sched_barrier(0);
            stage((i + 1) & 1, cbase + i + 1);
            __builtin_amdgcn_sched_barrier(0);
        }

        const char* lb = smem + (i & 1) * BUFB + l31 * ROWB;
#pragma unroll
        for (int s4 = 0; s4 < 4; ++s4) {
            const u32 kb0 = (u32)(w * 256 + s4 * 64 + g * 32);
            const float4 f0 = *(const float4*)(lb + ((kb0      ) ^ rsw));
            const float4 f1 = *(const float4*)(lb + ((kb0 + 16u) ^ rsw));
            float fv[8] = {f0.x, f0.y, f0.z, f0.w, f1.x, f1.y, f1.z, f1.w};
            F8 bh, bl;
#pragma unroll
            for (int e = 0; e < 8; ++e) {
                float f = fv[e];
                bh.us[e] = bft(f);
                bl.us[e] = bft(f - bfh(f));
                tsqp = fmaf(f, f, tsqp);
            }
            acc = __builtin_amdgcn_mfma_f32_32x32x16_bf16(ahc[s4].bf, bh.bf, acc, 0, 0, 0);
            acc = __builtin_amdgcn_mfma_f32_32x32x16_bf16(alc[s4].bf, bh.bf, acc, 0, 0, 0);
            acc = __builtin_amdgcn_mfma_f32_32x32x16_bf16(ahc[s4].bf, bl.bf, acc, 0, 0, 0);
        }
        if (i + 1 < nch) {
#pragma unroll
            for (int s4 = 0; s4 < 4; ++s4) { ahc[s4] = ahn[s4]; alc[s4] = aln[s4]; }
        }
    }
    __syncthreads();      // all compute done; smem reusable for the reduce

    // ---- cross-wave reduce (acc over k-quarters) + tsq ----
    tsqp += __shfl_xor(tsqp, 32);
    float* red = (float*)smem;
    if (w > 0) {
        float* dp = red + ((w - 1) * 64 + lane) * 16;
#pragma unroll
        for (int r = 0; r < 16; ++r) dp[r] = acc[r];
    }
    if (g == 0) red[3072 + w * 32 + l31] = tsqp;
    __syncthreads();
    if (w == 0) {
#pragma unroll
        for (int q = 0; q < 3; ++q) {
            const float* sp = red + (q * 64 + lane) * 16;
#pragma unroll
            for (int r = 0; r < 16; ++r) acc[r] += sp[r];
        }
        const float tsq = red[3072 + l31] + red[3072 + 32 + l31]
                        + red[3072 + 64 + l31] + red[3072 + 96 + l31];
        if (bid < NFULL) {
            float lg[16];
#pragma unroll
            for (int r = 0; r < 16; ++r) {
                lg[r] = c1 * acc[r] - c2 * tsq;
                int brow = (r & 3) + 8 * (r >> 2) + 4 * g;
                logits[(size_t)brow * NF32 + jt0 + l31] = lg[r];
            }
#pragma unroll
            for (int d = 1; d < 32; d <<= 1)
#pragma unroll
                for (int r = 0; r < 16; ++r)
                    lg[r] = fmaxf(lg[r], __shfl_xor(lg[r], d));
            if (l31 == 0) {
#pragma unroll
                for (int r = 0; r < 16; ++r) {
                    int brow = (r & 3) + 8 * (r >> 2) + 4 * g;
                    m_part[(size_t)brow * NFULL + bid] = lg[r];
                }
            }
        } else {
            const int t = tile - NFULL;
#pragma unroll
            for (int r = 0; r < 16; ++r) {
                int brow = (r & 3) + 8 * (r >> 2) + 4 * g;
                qpart[(((size_t)t * 4 + qp) * 32 + brow) * 32 + l31]
                    = c1 * acc[r] - c2 * tsq;
            }
        }
    }
}

// ---------------- K2b: row-max + tail-combine + deterministic selection ----------------
// mb = max over FULL tiles only (tail can exceed by ~EV spacing ~2; weights
// e^2 safe in f32; L renormalizes). seg==7 combines the 53 tail tiles' qpart
// into LDS and selects from there — k1c kernel eliminated.
__global__ __launch_bounds__(256) void k2b_select(
        const float* __restrict__ logits, const float* __restrict__ m_part,
        const float* __restrict__ qpart,
        int* __restrict__ idx, float* __restrict__ wts,
        int* __restrict__ cnt, float* __restrict__ lsum) {
    const int b   = blockIdx.x >> 3;
    const int seg = blockIdx.x & 7;
    const int tid = threadIdx.x;

    __shared__ float tail_lg[NTAIL];
    __shared__ int   soff[257];
    __shared__ float ssum[256];

    // global row max from per-tile maxima (12 KB)
    float mx = -3.0e38f;
    for (int i = tid; i < NFULL; i += 256)
        mx = fmaxf(mx, m_part[(size_t)b * NFULL + i]);
    ssum[tid] = mx;
    __syncthreads();
    for (int off = 128; off > 0; off >>= 1) {
        if (tid < off) ssum[tid] = fmaxf(ssum[tid], ssum[tid + off]);
        __syncthreads();
    }
    const float mb = ssum[0];
    __syncthreads();

    if (seg == 7) {
        for (int u = tid; u < NTAIL; u += 256) {
            const int t = u >> 5, j31 = u & 31;
            float sum = 0.0f;
#pragma unroll
            for (int p = 0; p < 4; ++p)
                sum += qpart[(((size_t)t * 4 + p) * 32 + b) * 32 + j31];
            tail_lg[u] = sum;
        }
        __syncthreads();
    }

    const int j0 = seg * SEGJ;
    const int j1 = (seg == 7) ? NTRAIN : (j0 + SEGJ);
    const float* lrow = logits + (size_t)b * NF32;

    auto getlg = [&](int j) -> float {
        return (j < NF32) ? lrow[j] : tail_lg[j - NF32];
    };

    int mycnt = 0;
    for (int j = j0 + tid; j < j1; j += 256)
        if (getlg(j) >= mb - THRESH) ++mycnt;

    soff[tid + 1] = mycnt;
    __syncthreads();
    if (tid == 0) {
        soff[0] = 0;
        for (int t = 1; t <= 256; ++t) soff[t] += soff[t - 1];
    }
    __syncthreads();

    int off = soff[tid];
    const int base = (b * NSEG + seg) * SEGCAP;
    float mysum = 0.0f;
    for (int j = j0 + tid; j < j1; j += 256) {
        float lg = getlg(j);
        if (lg >= mb - THRESH) {
            float wv = __expf(lg - mb);
            mysum += wv;
            if (off < SEGCAP) { idx[base + off] = j; wts[base + off] = wv; }
            ++off;
        }
    }
    ssum[tid] = mysum;
    __syncthreads();
    for (int o2 = 128; o2 > 0; o2 >>= 1) {
        if (tid < o2) ssum[tid] += ssum[tid + o2];
        __syncthreads();
    }
    if (tid == 0) {
        lsum[b * NSEG + seg] = ssum[0];
        cnt[b * NSEG + seg]  = min(soff[256], SEGCAP);
    }
}

// ---------------- K3: gather-PV over selected rows + final output (all f32) ----------------
__global__ __launch_bounds__(256) void k3_gather(
        const float* __restrict__ x, const float* __restrict__ train,
        const int* __restrict__ idx, const float* __restrict__ wts,
        const int* __restrict__ cnt, const float* __restrict__ lsum,
        const float* __restrict__ alphas, const int* __restrict__ tptr,
        float* __restrict__ out) {
    const int blk  = blockIdx.x;       // b*12 + dseg
    const int b    = blk / 12;
    const int dseg = blk % 12;
    const int d    = dseg * 256 + threadIdx.x;

    const float ab  = alphas[tptr[0]];
    const float s   = sqrtf(ab);
    const float om  = 1.0f - ab;
    const float inv = 1.0f / sqrtf(om);

    float L = 0.0f;
#pragma unroll
    for (int sg = 0; sg < NSEG; ++sg) L += lsum[b * NSEG + sg];

    float acc = 0.0f;
    for (int sg = 0; sg < NSEG; ++sg) {
        const int n    = cnt[b * NSEG + sg];
        const int base = (b * NSEG + sg) * SEGCAP;
        for (int i = 0; i < n; ++i) {
            const int   j = idx[base + i];
            const float w = wts[base + i];
            acc = fmaf(w, train[(size_t)j * DIM + d], acc);
        }
    }
    const size_t o = (size_t)b * DIM + d;
    out[o] = inv * x[o] - s * inv * (acc / L);
}

extern "C" void kernel_launch(void* const* d_in, const int* in_sizes, int n_in,
                              void* d_out, int out_size, void* d_ws, size_t ws_size,
                              hipStream_t stream) {
    const float* x      = (const float*)d_in[0];
    const float* train  = (const float*)d_in[1];
    const float* alphas = (const float*)d_in[2];
    const int*   tptr   = (const int*)d_in[3];
    float* out = (float*)d_out;

    char* ws = (char*)d_ws;
    float* logits = (float*)ws;                         // 12,582,912 B
    float* m_part = (float*)(ws + 12582912);            //    393,216 B
    float* qpart  = (float*)(ws + 12976128);            //    868,352 B
    float* lsum   = (float*)(ws + 13844480);            //      1,024 B
    int*   cnt    = (int*)(ws + 13845504);              //      1,024 B
    int*   idx    = (int*)(ws + 13846528);              //  1,048,576 B
    float* wts    = (float*)(ws + 14895104);            //  1,048,576 B
    u16*   xfh    = (u16*)(ws + 15943680);              //    196,608 B
    u16*   xfl    = (u16*)(ws + 16140288);              //    196,608 B

    k0_split_x_v2<<<48, 256, 0, stream>>>(x, xfh, xfl);
    k1_logits_v9<<<NFULL + NREM * 4, 256, 0, stream>>>(train, xfh, xfl, alphas,
                                                       tptr, logits, m_part, qpart);
    k2b_select<<<BATCH * NSEG, 256, 0, stream>>>(logits, m_part, qpart,
                                                 idx, wts, cnt, lsum);
    k3_gather<<<BATCH * 12, 256, 0, stream>>>(x, train, idx, wts, cnt, lsum,
                                              alphas, tptr, out);
}

// Round 16
// 266.814 us; speedup vs baseline: 1.3684x; 1.0005x over previous
//
#include <hip/hip_runtime.h>

#define BATCH  32
#define DIM    3072
#define NTRAIN 100000
#define NTILE1 3125          /* j-tiles of 32 */
#define NFULL  3072          /* full-k tiles (= 512 slots x 6 rounds exactly) */
#define NREM   53            /* remainder tiles, k-split 4-ways */
#define NF32   98304         /* NFULL*32 */
#define NTAIL  1696          /* NTRAIN - NF32 */

/* k1 v9: 1KB-granule staging, double buffer */
#define KCH    256           /* k per chunk */
#define NCH    12            /* chunks, full tile */
#define NCHQ   3             /* chunks, quarter tile */
#define ROWB   1024          /* bytes per row per chunk */
#define BUFB   (32 * ROWB)   /* 32768 B per buffer; 2 buffers = 64 KB */

/* selection */
#define NSEG   8
#define SEGJ   12500
#define SEGCAP 1024
#define THRESH 25.0f

typedef __bf16 bf16x8 __attribute__((ext_vector_type(8)));
typedef float  f32x16 __attribute__((ext_vector_type(16)));
typedef unsigned short u16;
typedef unsigned int   u32;

union F8 { u16 us[8]; u32 ui[4]; uint4 u4; bf16x8 bf; };

__device__ __forceinline__ u16   bft(float f){ return (u16)(__float_as_uint(f) >> 16); }
__device__ __forceinline__ float bfh(float f){ return __uint_as_float(__float_as_uint(f) & 0xFFFF0000u); }

// ---------------- K0: split x into bf16 hi/lo, fragment-ordered ----------------
__global__ __launch_bounds__(256) void k0_split_x_v2(
        const float* __restrict__ x, u16* __restrict__ xfh, u16* __restrict__ xfl) {
    int task = blockIdx.x * 256 + threadIdx.x;   // 12288 tasks
    if (task >= 12288) return;
    int kb  = task >> 6;
    int rem = task & 63;
    int r   = rem >> 1;
    int g   = rem & 1;
    const float* src = x + r * DIM + kb * 16 + g * 8;
    float4 A = *(const float4*)(src);
    float4 B = *(const float4*)(src + 4);
    float fv[8] = {A.x, A.y, A.z, A.w, B.x, B.y, B.z, B.w};
    F8 h, l;
#pragma unroll
    for (int e = 0; e < 8; ++e) {
        h.us[e] = bft(fv[e]);
        l.us[e] = bft(fv[e] - bfh(fv[e]));
    }
    size_t off = (size_t)kb * 512 + r * 16 + g * 8;
    *(uint4*)(xfh + off) = h.u4;
    *(uint4*)(xfl + off) = l.u4;
}

// ---------------- K1 v9: logits; 1KB staging granule, double buffer ----------------
// bid < NFULL: full tile (12 chunks). bid >= NFULL: quarter tile (3 chunks)
// -> scaled partials to qpart. Chunk period >> HBM latency -> depth-1
// prefetch with __syncthreads drain is throughput-optimal.
__global__ __launch_bounds__(256) void k1_logits_v9(
        const float* __restrict__ train,
        const u16* __restrict__ xfh, const u16* __restrict__ xfl,
        const float* __restrict__ alphas, const int* __restrict__ tptr,
        float* __restrict__ logits, float* __restrict__ m_part,
        float* __restrict__ qpart) {
    __shared__ __align__(16) char smem[2 * BUFB];
    const int tid  = threadIdx.x;
    const int lane = tid & 63;
    const int w    = tid >> 6;
    const int l31  = lane & 31;
    const int g    = lane >> 5;
    const int bid  = blockIdx.x;

    int tile, cbase, nch, qp = 0;
    if (bid < NFULL) { tile = bid; cbase = 0; nch = NCH; }
    else {
        int rem = bid - NFULL;
        tile  = NFULL + (rem >> 2);
        qp    = rem & 3;
        cbase = qp * NCHQ;
        nch   = NCHQ;
    }
    const int jt0 = tile * 32;

    const float ab = alphas[tptr[0]];
    const float s  = sqrtf(ab);
    const float om = 1.0f - ab;
    const float c1 = s / om;
    const float c2 = ab / (2.0f * om);

    const char* gblk = (const char*)train + (size_t)jt0 * (DIM * 4);

    f32x16 acc;
#pragma unroll
    for (int r = 0; r < 16; ++r) acc[r] = 0.0f;
    float tsqp = 0.0f;

    // stage chunk c into buffer buf: 8 full-wave 1KB instrs/wave (one row each),
    // source pre-swizzled col ^= (row&7)<<4, LDS dest linear (rule #21).
    auto stage = [&](int buf, int c) {
#pragma unroll
        for (int i = 0; i < 8; ++i) {
            const int r = w * 8 + i;
            const u32 colS = (u32)(lane << 4) ^ ((u32)(r & 7) << 4);
            const char* src = gblk + (size_t)r * (DIM * 4) + c * (KCH * 4) + colS;
            char* dst = smem + buf * BUFB + r * ROWB;
            __builtin_amdgcn_global_load_lds(
                (const __attribute__((address_space(1))) unsigned int*)src,
                (__attribute__((address_space(3))) unsigned int*)dst,
                16, 0, 0);
        }
    };
    // x-fragment loads for chunk c: 8 dense 1KB loads per wave
    auto ldx = [&](int c, F8* ah, F8* al) {
#pragma unroll
        for (int s4 = 0; s4 < 4; ++s4) {
            const int kb16 = c * 16 + w * 4 + s4;
            const size_t off = (size_t)kb16 * 512 + l31 * 16 + g * 8;
            ah[s4].u4 = *(const uint4*)(xfh + off);
            al[s4].u4 = *(const uint4*)(xfl + off);
        }
    };

    F8 ahc[4], alc[4];
    ldx(cbase, ahc, alc);
    __builtin_amdgcn_sched_barrier(0);
    stage(0, cbase);
    __builtin_amdgcn_sched_barrier(0);

    const u32 rsw = ((u32)(l31 & 7)) << 4;

    for (int i = 0; i < nch; ++i) {
        __syncthreads();           // drains vmcnt: stage(i)+ldx(i) landed; buf swap safe

        F8 ahn[4], aln[4];
        if (i + 1 < nch) {
            ldx(cbase + i + 1, ahn, aln);
            __builtin_amdgcn_sched_barrier(0);
            stage((i + 1) & 1, cbase + i + 1);
            __builtin_amdgcn_sched_barrier(0);
        }

        const char* lb = smem + (i & 1) * BUFB + l31 * ROWB;
#pragma unroll
        for (int s4 = 0; s4 < 4; ++s4) {
            const u32 kb0 = (u32)(w * 256 + s4 * 64 + g * 32);
            const float4 f0 = *(const float4*)(lb + ((kb0      ) ^ rsw));
            const float4 f1 = *(const float4*)(lb + ((kb0 + 16u) ^ rsw));
            float fv[8] = {f0.x, f0.y, f0.z, f0.w, f1.x, f1.y, f1.z, f1.w};
            F8 bh, bl;
#pragma unroll
            for (int e = 0; e < 8; ++e) {
                float f = fv[e];
                bh.us[e] = bft(f);
                bl.us[e] = bft(f - bfh(f));
                tsqp = fmaf(f, f, tsqp);
            }
            acc = __builtin_amdgcn_mfma_f32_32x32x16_bf16(ahc[s4].bf, bh.bf, acc, 0, 0, 0);
            acc = __builtin_amdgcn_mfma_f32_32x32x16_bf16(alc[s4].bf, bh.bf, acc, 0, 0, 0);
            acc = __builtin_amdgcn_mfma_f32_32x32x16_bf16(ahc[s4].bf, bl.bf, acc, 0, 0, 0);
        }
        if (i + 1 < nch) {
#pragma unroll
            for (int s4 = 0; s4 < 4; ++s4) { ahc[s4] = ahn[s4]; alc[s4] = aln[s4]; }
        }
    }
    __syncthreads();      // all compute done; smem reusable for the reduce

    // ---- cross-wave reduce (acc over k-quarters) + tsq ----
    tsqp += __shfl_xor(tsqp, 32);
    float* red = (float*)smem;
    if (w > 0) {
        float* dp = red + ((w - 1) * 64 + lane) * 16;
#pragma unroll
        for (int r = 0; r < 16; ++r) dp[r] = acc[r];
    }
    if (g == 0) red[3072 + w * 32 + l31] = tsqp;
    __syncthreads();
    if (w == 0) {
#pragma unroll
        for (int q = 0; q < 3; ++q) {
            const float* sp = red + (q * 64 + lane) * 16;
#pragma unroll
            for (int r = 0; r < 16; ++r) acc[r] += sp[r];
        }
        const float tsq = red[3072 + l31] + red[3072 + 32 + l31]
                        + red[3072 + 64 + l31] + red[3072 + 96 + l31];
        if (bid < NFULL) {
            float lg[16];
#pragma unroll
            for (int r = 0; r < 16; ++r) {
                lg[r] = c1 * acc[r] - c2 * tsq;
                int brow = (r & 3) + 8 * (r >> 2) + 4 * g;
                logits[(size_t)brow * NF32 + jt0 + l31] = lg[r];
            }
#pragma unroll
            for (int d = 1; d < 32; d <<= 1)
#pragma unroll
                for (int r = 0; r < 16; ++r)
                    lg[r] = fmaxf(lg[r], __shfl_xor(lg[r], d));
            if (l31 == 0) {
#pragma unroll
                for (int r = 0; r < 16; ++r) {
                    int brow = (r & 3) + 8 * (r >> 2) + 4 * g;
                    m_part[(size_t)brow * NFULL + bid] = lg[r];
                }
            }
        } else {
            const int t = tile - NFULL;
#pragma unroll
            for (int r = 0; r < 16; ++r) {
                int brow = (r & 3) + 8 * (r >> 2) + 4 * g;
                qpart[(((size_t)t * 4 + qp) * 32 + brow) * 32 + l31]
                    = c1 * acc[r] - c2 * tsq;
            }
        }
    }
}

// ---------------- K2b: row-max + tail-combine + deterministic selection ----------------
// mb = max over FULL tiles only (tail can exceed by ~EV spacing ~2; weights
// e^2 safe in f32; L renormalizes). seg==7 combines the 53 tail tiles' qpart
// into LDS and selects from there — k1c kernel eliminated.
__global__ __launch_bounds__(256) void k2b_select(
        const float* __restrict__ logits, const float* __restrict__ m_part,
        const float* __restrict__ qpart,
        int* __restrict__ idx, float* __restrict__ wts,
        int* __restrict__ cnt, float* __restrict__ lsum) {
    const int b   = blockIdx.x >> 3;
    const int seg = blockIdx.x & 7;
    const int tid = threadIdx.x;

    __shared__ float tail_lg[NTAIL];
    __shared__ int   soff[257];
    __shared__ float ssum[256];

    // global row max from per-tile maxima (12 KB)
    float mx = -3.0e38f;
    for (int i = tid; i < NFULL; i += 256)
        mx = fmaxf(mx, m_part[(size_t)b * NFULL + i]);
    ssum[tid] = mx;
    __syncthreads();
    for (int off = 128; off > 0; off >>= 1) {
        if (tid < off) ssum[tid] = fmaxf(ssum[tid], ssum[tid + off]);
        __syncthreads();
    }
    const float mb = ssum[0];
    __syncthreads();

    if (seg == 7) {
        for (int u = tid; u < NTAIL; u += 256) {
            const int t = u >> 5, j31 = u & 31;
            float sum = 0.0f;
#pragma unroll
            for (int p = 0; p < 4; ++p)
                sum += qpart[(((size_t)t * 4 + p) * 32 + b) * 32 + j31];
            tail_lg[u] = sum;
        }
        __syncthreads();
    }

    const int j0 = seg * SEGJ;
    const int j1 = (seg == 7) ? NTRAIN : (j0 + SEGJ);
    const float* lrow = logits + (size_t)b * NF32;

    auto getlg = [&](int j) -> float {
        return (j < NF32) ? lrow[j] : tail_lg[j - NF32];
    };

    int mycnt = 0;
    for (int j = j0 + tid; j < j1; j += 256)
        if (getlg(j) >= mb - THRESH) ++mycnt;

    soff[tid + 1] = mycnt;
    __syncthreads();
    if (tid == 0) {
        soff[0] = 0;
        for (int t = 1; t <= 256; ++t) soff[t] += soff[t - 1];
    }
    __syncthreads();

    int off = soff[tid];
    const int base = (b * NSEG + seg) * SEGCAP;
    float mysum = 0.0f;
    for (int j = j0 + tid; j < j1; j += 256) {
        float lg = getlg(j);
        if (lg >= mb - THRESH) {
            float wv = __expf(lg - mb);
            mysum += wv;
            if (off < SEGCAP) { idx[base + off] = j; wts[base + off] = wv; }
            ++off;
        }
    }
    ssum[tid] = mysum;
    __syncthreads();
    for (int o2 = 128; o2 > 0; o2 >>= 1) {
        if (tid < o2) ssum[tid] += ssum[tid + o2];
        __syncthreads();
    }
    if (tid == 0) {
        lsum[b * NSEG + seg] = ssum[0];
        cnt[b * NSEG + seg]  = min(soff[256], SEGCAP);
    }
}

// ---------------- K3: gather-PV over selected rows + final output (all f32) ----------------
__global__ __launch_bounds__(256) void k3_gather(
        const float* __restrict__ x, const float* __restrict__ train,
        const int* __restrict__ idx, const float* __restrict__ wts,
        const int* __restrict__ cnt, const float* __restrict__ lsum,
        const float* __restrict__ alphas, const int* __restrict__ tptr,
        float* __restrict__ out) {
    const int blk  = blockIdx.x;       // b*12 + dseg
    const int b    = blk / 12;
    const int dseg = blk % 12;
    const int d    = dseg * 256 + threadIdx.x;

    const float ab  = alphas[tptr[0]];
    const float s   = sqrtf(ab);
    const float om  = 1.0f - ab;
    const float inv = 1.0f / sqrtf(om);

    float L = 0.0f;
#pragma unroll
    for (int sg = 0; sg < NSEG; ++sg) L += lsum[b * NSEG + sg];

    float acc = 0.0f;
    for (int sg = 0; sg < NSEG; ++sg) {
        const int n    = cnt[b * NSEG + sg];
        const int base = (b * NSEG + sg) * SEGCAP;
        for (int i = 0; i < n; ++i) {
            const int   j = idx[base + i];
            const float w = wts[base + i];
            acc = fmaf(w, train[(size_t)j * DIM + d], acc);
        }
    }
    const size_t o = (size_t)b * DIM + d;
    out[o] = inv * x[o] - s * inv * (acc / L);
}

extern "C" void kernel_launch(void* const* d_in, const int* in_sizes, int n_in,
                              void* d_out, int out_size, void* d_ws, size_t ws_size,
                              hipStream_t stream) {
    const float* x      = (const float*)d_in[0];
    const float* train  = (const float*)d_in[1];
    const float* alphas = (const float*)d_in[2];
    const int*   tptr   = (const int*)d_in[3];
    float* out = (float*)d_out;

    char* ws = (char*)d_ws;
    float* logits = (float*)ws;                         // 12,582,912 B
    float* m_part = (float*)(ws + 12582912);            //    393,216 B
    float* qpart  = (float*)(ws + 12976128);            //    868,352 B
    float* lsum   = (float*)(ws + 13844480);            //      1,024 B
    int*   cnt    = (int*)(ws + 13845504);              //      1,024 B
    int*   idx    = (int*)(ws + 13846528);              //  1,048,576 B
    float* wts    = (float*)(ws + 14895104);            //  1,048,576 B
    u16*   xfh    = (u16*)(ws + 15943680);              //    196,608 B
    u16*   xfl    = (u16*)(ws + 16140288);              //    196,608 B

    k0_split_x_v2<<<48, 256, 0, stream>>>(x, xfh, xfl);
    k1_logits_v9<<<NFULL + NREM * 4, 256, 0, stream>>>(train, xfh, xfl, alphas,
                                                       tptr, logits, m_part, qpart);
    k2b_select<<<BATCH * NSEG, 256, 0, stream>>>(logits, m_part, qpart,
                                                 idx, wts, cnt, lsum);
    k3_gather<<<BATCH * 12, 256, 0, stream>>>(x, train, idx, wts, cnt, lsum,
                                              alphas, tptr, out);
}